// Round 8
// baseline (4634.693 us; speedup 1.0000x reference)
//
#include <hip/hip_runtime.h>
#include <math.h>

constexpr int B = 24, HH = 8;
constexpr int NN = 256, MQ = 64;
constexpr int EC = 364;

#define PI_2 1.5707963267948966f

// stats partials layout: parts[row][4][2], row = b*64+d
__device__ __forceinline__ void combine_stats(const float* __restrict__ parts,
                                              int row, int NT, float Lf,
                                              float& mu, float& inv) {
  float s = 0.f, q = 0.f;
  for (int t = 0; t < NT; ++t) {
    s += parts[((size_t)row * 4 + t) * 2];
    q += parts[((size_t)row * 4 + t) * 2 + 1];
  }
  mu = s / Lf;
  float var = (q - s * mu) / (Lf - 1.f);
  if (var < 0.f) var = 0.f;
  inv = 1.f / (sqrtf(var) + 1e-6f);
}

// ---------------- positional encoding table: tab[d*256+l] ----------------
__global__ void k_postab(float* __restrict__ tab) {
  int d = blockIdx.x, l = threadIdx.x;
  float fr = ((d & 1) == 0) ? powf(10000.f, -(float)d / 64.f)
                            : -powf(10000.f, -(float)(d - 1) / 64.f);
  float ph = (d & 1) ? PI_2 : 0.f;
  tab[d * 256 + l] = sinf(sinf((float)l * fr + ph));
}

// ---- X = (COPY? src : X) + tab ; emit per-tile row stats -----------------
template<bool COPY>
__global__ void k_posadd_stats(float* __restrict__ X, const float* __restrict__ src,
                               const float* __restrict__ tab, float* __restrict__ parts,
                               int L) {
  int row = blockIdx.x * 4 + (threadIdx.x >> 6);
  int lane = threadIdx.x & 63;
  int d = row & 63;
  float* xr = X + (size_t)row * L;
  const float* sr = COPY ? (src + (size_t)row * L) : xr;
  int NT = L >> 6;
  for (int t = 0; t < NT; ++t) {
    int l = t * 64 + lane;
    float v = sr[l] + tab[d * 256 + l];
    xr[l] = v;
    float s = v, q = v * v;
#pragma unroll
    for (int o = 32; o > 0; o >>= 1) { s += __shfl_xor(s, o); q += __shfl_xor(q, o); }
    if (lane == 0) {
      parts[((size_t)row * 4 + t) * 2] = s;
      parts[((size_t)row * 4 + t) * 2 + 1] = q;
    }
  }
}

// ---- fused: normalize -> dwconv(K) -> pw matmul -> relu -> +res -> X -----
// also emits per-tile row stats of the new X.
template<int K>
__global__ __launch_bounds__(256) void k_fconv(
    float* __restrict__ X, const float* __restrict__ dw, const float* __restrict__ pw,
    const float* __restrict__ partsIn, float* __restrict__ partsOut, int L) {
  constexpr int H = K / 2, SW = 64 + 2 * H;
  __shared__ float smu[64], sinv[64];
  __shared__ float sN[64 * SW];
  __shared__ float sD[64 * 65];
  __shared__ float sWt[4096];
  int b = blockIdx.x, lt = blockIdx.y * 64;
  int tid = threadIdx.x;
  int NT = L >> 6;
  if (tid < 64) combine_stats(partsIn, b * 64 + tid, NT, (float)L, smu[tid], sinv[tid]);
  for (int i = tid; i < 4096; i += 256) sWt[i] = pw[i];
  __syncthreads();
  float* Xb = X + (size_t)b * 64 * L;
  for (int i = tid; i < 64 * SW; i += 256) {
    int c = i / SW, jj = i % SW;
    int gl = lt + jj - H;
    sN[i] = (gl >= 0 && gl < L) ? (Xb[(size_t)c * L + gl] - smu[c]) * sinv[c] : 0.f;
  }
  __syncthreads();
  for (int i = tid; i < 4096; i += 256) {
    int c = i >> 6, l = i & 63;
    float acc = 0.f;
#pragma unroll
    for (int k = 0; k < K; ++k) acc += sN[c * SW + l + k] * dw[c * K + k];
    sD[c * 65 + l] = acc;
  }
  __syncthreads();
  int l = tid & 63, og = tid >> 6;
  float acc[16];
#pragma unroll
  for (int j = 0; j < 16; ++j) acc[j] = 0.f;
  for (int c = 0; c < 64; ++c) {
    float av = sD[c * 65 + l];
#pragma unroll
    for (int j = 0; j < 16; ++j) acc[j] += sWt[(og * 16 + j) * 64 + c] * av;
  }
  __syncthreads();   // done reading sD
#pragma unroll
  for (int j = 0; j < 16; ++j) {
    int o = og * 16 + j;
    float v = Xb[(size_t)o * L + lt + l] + fmaxf(acc[j], 0.f);
    Xb[(size_t)o * L + lt + l] = v;
    sD[o * 65 + l] = v;
  }
  __syncthreads();
  if (tid < 64) {
    int o = tid;
    float s = 0.f, q = 0.f;
    for (int l2 = 0; l2 < 64; ++l2) { float v = sD[o * 65 + l2]; s += v; q += v * v; }
    partsOut[((size_t)(b * 64 + o) * 4 + blockIdx.y) * 2] = s;
    partsOut[((size_t)(b * 64 + o) * 4 + blockIdx.y) * 2 + 1] = q;
  }
}

// ---- generic 64x64 matmul: out = (res +) act(W . (norm?)A) ; opt stats ---
template<bool NORM, bool RELU, bool STATS>
__global__ __launch_bounds__(256) void k_matmul2(
    const float* __restrict__ A, const float* __restrict__ W,
    const float* __restrict__ res, float* __restrict__ out,
    const float* __restrict__ partsIn, float* __restrict__ partsOut, int L) {
  __shared__ float sA[64 * 65];
  __shared__ float sW[4096];
  __shared__ float smu[64], sinv[64];
  int b = blockIdx.x, lt = blockIdx.y * 64;
  int tid = threadIdx.x;
  int NT = L >> 6;
  if (NORM && tid < 64) combine_stats(partsIn, b * 64 + tid, NT, (float)L, smu[tid], sinv[tid]);
  const float* Wb = W + (size_t)b * 4096;
  for (int i = tid; i < 4096; i += 256) sW[i] = Wb[i];
  if (NORM) __syncthreads();
  const float* Ab = A + (size_t)b * 64 * L;
  for (int i = tid; i < 4096; i += 256) {
    int c = i >> 6, ll = i & 63;
    float v = Ab[(size_t)c * L + lt + ll];
    if (NORM) v = (v - smu[c]) * sinv[c];
    sA[c * 65 + ll] = v;
  }
  __syncthreads();
  int l = tid & 63, og = tid >> 6;
  float acc[16];
#pragma unroll
  for (int j = 0; j < 16; ++j) acc[j] = 0.f;
  for (int c = 0; c < 64; ++c) {
    float av = sA[c * 65 + l];
#pragma unroll
    for (int j = 0; j < 16; ++j) acc[j] += sW[(og * 16 + j) * 64 + c] * av;
  }
  if (STATS) __syncthreads();
#pragma unroll
  for (int j = 0; j < 16; ++j) {
    int o = og * 16 + j;
    float v = acc[j];
    if (RELU) v = fmaxf(v, 0.f);
    size_t idx = ((size_t)b * 64 + o) * L + lt + l;
    v += res[idx];
    out[idx] = v;
    if (STATS) sA[o * 65 + l] = v;
  }
  if (STATS) {
    __syncthreads();
    if (tid < 64) {
      int o = tid;
      float s = 0.f, q = 0.f;
      for (int l2 = 0; l2 < 64; ++l2) { float v = sA[o * 65 + l2]; s += v; q += v * v; }
      partsOut[((size_t)(b * 64 + o) * 4 + blockIdx.y) * 2] = s;
      partsOut[((size_t)(b * 64 + o) * 4 + blockIdx.y) * 2 + 1] = q;
    }
  }
}

// ---- fused resize: M0[b,o,l] = sum_c pw[o,c] * dw5(Xcat)[b,c,l] ----------
__global__ __launch_bounds__(256) void k_resize(
    const float* __restrict__ Xcat, const float* __restrict__ dw,
    const float* __restrict__ pw, float* __restrict__ out) {
  __shared__ float sA[64 * 64];
  int b = blockIdx.x, lt = blockIdx.y * 64;
  int l = threadIdx.x & 63, og = threadIdx.x >> 6;
  float acc[16];
#pragma unroll
  for (int j = 0; j < 16; ++j) acc[j] = 0.f;
  for (int c0 = 0; c0 < 256; c0 += 64) {
    __syncthreads();
    for (int i = threadIdx.x; i < 4096; i += 256) {
      int c = (i >> 6) + c0, ll = (i & 63) + lt;
      const float* xr = Xcat + ((size_t)b * 256 + c) * 256;
      float a = 0.f;
#pragma unroll
      for (int k = 0; k < 5; ++k) {
        int p = ll + k - 2;
        if (p >= 0 && p < 256) a += xr[p] * dw[c * 5 + k];
      }
      sA[i] = a;
    }
    __syncthreads();
    for (int c = 0; c < 64; ++c) {
      float av = sA[c * 64 + l];
#pragma unroll
      for (int j = 0; j < 16; ++j)
        acc[j] += pw[(size_t)(og * 16 + j) * 256 + c0 + c] * av;
    }
  }
#pragma unroll
  for (int j = 0; j < 16; ++j)
    out[((size_t)b * 64 + og * 16 + j) * 256 + lt + l] = acc[j];
}

// ---- self-attention with inline norm, online softmax ---------------------
__global__ __launch_bounds__(256) void k_att(
    const float* __restrict__ X, const float* __restrict__ partsIn,
    const float* __restrict__ wq, const float* __restrict__ wk,
    const float* __restrict__ wv, float* __restrict__ hc, int L) {
  int h = blockIdx.x, b = blockIdx.y;
  __shared__ float smu[64], sinv[64];
  __shared__ float sX[64 * 65];
  __shared__ float sQ[8 * 256], sK8[8 * 256], sV[8 * 256];
  __shared__ float swq[512], swk[512], swv[512];
  int tid = threadIdx.x;
  int NT = L >> 6;
  if (tid < 64) combine_stats(partsIn, b * 64 + tid, NT, (float)L, smu[tid], sinv[tid]);
  size_t woff = (size_t)(h * B + b) * 512;
  for (int i = tid; i < 512; i += 256) {
    swq[i] = wq[woff + i]; swk[i] = wk[woff + i]; swv[i] = wv[woff + i];
  }
  __syncthreads();
  const float* Xb = X + (size_t)b * 64 * L;
  for (int lt = 0; lt < L; lt += 64) {
    for (int i = tid; i < 4096; i += 256) {
      int d = i >> 6, l = i & 63;
      sX[d * 65 + l] = (Xb[(size_t)d * L + lt + l] - smu[d]) * sinv[d];
    }
    __syncthreads();
    for (int i = tid; i < 512; i += 256) {
      int k = i >> 6, l = i & 63;
      float aq = 0.f, ak = 0.f, av = 0.f;
      for (int d = 0; d < 64; ++d) {
        float x = sX[d * 65 + l];
        aq += swq[k * 64 + d] * x;
        ak += swk[k * 64 + d] * x;
        av += swv[k * 64 + d] * x;
      }
      sQ[k * L + lt + l] = aq; sK8[k * L + lt + l] = ak; sV[k * L + lt + l] = av;
    }
    __syncthreads();
  }
  const float scale = 0.35355339059327373f;  // 1/sqrt(8)
  for (int m = tid; m < L; m += 256) {
    float kc[8];
#pragma unroll
    for (int k = 0; k < 8; ++k) kc[k] = sK8[k * L + m];
    float mx = -1e30f, sum = 0.f, acc[8];
#pragma unroll
    for (int v = 0; v < 8; ++v) acc[v] = 0.f;
    for (int l = 0; l < L; ++l) {
      float s = 0.f;
#pragma unroll
      for (int k = 0; k < 8; ++k) s += sQ[k * L + l] * kc[k];
      s *= scale;
      if (s <= mx) {
        float p = __expf(s - mx);
        sum += p;
#pragma unroll
        for (int v = 0; v < 8; ++v) acc[v] += p * sV[v * L + l];
      } else {
        float corr = __expf(mx - s);
        sum = sum * corr + 1.f;
#pragma unroll
        for (int v = 0; v < 8; ++v) acc[v] = acc[v] * corr + sV[v * L + l];
        mx = s;
      }
    }
    float is = 1.f / sum;
    for (int v = 0; v < 8; ++v)
      hc[((size_t)b * 64 + h * 8 + v) * L + m] = acc[v] * is;
  }
}

// ---- fused char embed ----------------------------------------------------
__global__ __launch_bounds__(256) void k_charembed(
    const int* __restrict__ cid, const float* __restrict__ ctab,
    const float* __restrict__ dw, const float* __restrict__ db,
    const float* __restrict__ pw, const float* __restrict__ pb,
    float* __restrict__ out, int Ln) {
  int n = blockIdx.x, b = blockIdx.y;
  __shared__ float dwo[200 * 16];
  __shared__ int sid[5][16];
  __shared__ float red[256];
  int tid = threadIdx.x;
  if (tid < 80) {
    int kn = tid / 16, cn = tid % 16;
    int nn = n + kn - 2;
    sid[kn][cn] = (nn >= 0 && nn < Ln) ? cid[((size_t)b * Ln + nn) * 16 + cn] : -1;
  }
  __syncthreads();
  for (int i = tid; i < 200 * 16; i += 256) {
    int ce = i / 16, cn = i % 16;
    float acc = db[ce];
    const float* wcc = dw + ce * 25;
#pragma unroll
    for (int kn = 0; kn < 5; ++kn)
#pragma unroll
      for (int kc = 0; kc < 5; ++kc) {
        int cc = cn + kc - 2;
        if (cc < 0 || cc >= 16) continue;
        int id = sid[kn][cc];
        if (id >= 0) acc += ctab[id * 200 + ce] * wcc[kn * 5 + kc];
      }
    dwo[i] = acc;
  }
  __syncthreads();
  int o = tid & 63, q = tid >> 6;
  float mx = -1e30f;
  const float* pwr = pw + o * 200;
  for (int cn = q; cn < 16; cn += 4) {
    float acc = pb[o];
    for (int ce = 0; ce < 200; ++ce) acc += pwr[ce] * dwo[ce * 16 + cn];
    mx = fmaxf(mx, acc);
  }
  red[tid] = mx;
  __syncthreads();
  if (q == 0) {
    mx = fmaxf(fmaxf(red[o], red[64 + o]), fmaxf(red[128 + o], red[192 + o]));
    out[((size_t)b * 64 + o) * Ln + n] = fmaxf(mx, 0.f);
  }
}

// ---- fused emb conv ------------------------------------------------------
__global__ void k_embconv(const float* __restrict__ chx, const int* __restrict__ wid,
                          const float* __restrict__ wtab, const float* __restrict__ dw,
                          const float* __restrict__ db, const float* __restrict__ pw,
                          const float* __restrict__ pb, float* __restrict__ out, int Ln) {
  int n = blockIdx.x, b = blockIdx.y;
  __shared__ float dwc[EC];
  __shared__ int sw[5];
  int tid = threadIdx.x;
  if (tid < 5) {
    int nn = n + tid - 2;
    sw[tid] = (nn >= 0 && nn < Ln) ? wid[(size_t)b * Ln + nn] : -1;
  }
  __syncthreads();
  for (int ch = tid; ch < EC; ch += 64) {
    float acc = db[ch];
#pragma unroll
    for (int k = 0; k < 5; ++k) {
      int nn = n + k - 2;
      float v = 0.f;
      if (nn >= 0 && nn < Ln) {
        if (ch < 64) v = chx[((size_t)b * 64 + ch) * Ln + nn];
        else v = wtab[(size_t)sw[k] * 300 + (ch - 64)];
      }
      acc += v * dw[ch * 5 + k];
    }
    dwc[ch] = acc;
  }
  __syncthreads();
  int o = tid;
  float acc = pb[o];
  const float* pwr = pw + o * EC;
  for (int c = 0; c < EC; ++c) acc += pwr[c] * dwc[c];
  out[((size_t)b * 64 + o) * Ln + n] = acc;
}

// ---------------- highway -------------------------------------------------
__global__ void k_highway(const float* __restrict__ inx, const float* __restrict__ lw,
                          const float* __restrict__ lb, const float* __restrict__ gw,
                          const float* __restrict__ gb, float* __restrict__ out, int Ln) {
  int n = blockIdx.x, b = blockIdx.y;
  __shared__ float x[64], xn[64];
  int o = threadIdx.x;
  x[o] = inx[((size_t)b * 64 + o) * Ln + n];
  __syncthreads();
  for (int layer = 0; layer < 2; ++layer) {
    const float* lwr = lw + (layer * 64 + o) * 64;
    const float* gwr = gw + (layer * 64 + o) * 64;
    float gl = gb[layer * 64 + o], nl = lb[layer * 64 + o];
    for (int d = 0; d < 64; ++d) { gl += gwr[d] * x[d]; nl += lwr[d] * x[d]; }
    float g = 1.f / (1.f + __expf(-gl));
    float r = fmaxf(nl, 0.f);
    xn[o] = g * r + (1.f - g) * x[o];
    __syncthreads();
    x[o] = xn[o];
    __syncthreads();
  }
  out[((size_t)b * 64 + o) * Ln + n] = x[o];
}

// ---------------- context-query attention ---------------------------------
// S + row-softmax stats fused (each wave owns one full row)
__global__ __launch_bounds__(256) void k_cqS(const float* __restrict__ C,
                                             const float* __restrict__ Q,
                                             const float* __restrict__ w,
                                             float* __restrict__ S,
                                             float* __restrict__ rmax,
                                             float* __restrict__ rsum) {
  int b = blockIdx.x, nt = blockIdx.y * 64;
  __shared__ float sQ[4096], sC[4096], ct[64], qt[64], swb[192];
  const float* Cb = C + (size_t)b * 64 * 256;
  const float* Qb = Q + (size_t)b * 4096;
  const float* wb = w + (size_t)b * 192;
  if (threadIdx.x < 192) swb[threadIdx.x] = wb[threadIdx.x];
  for (int i = threadIdx.x; i < 4096; i += 256) {
    int d = i >> 6, m = i & 63;
    sQ[i] = Qb[d * 64 + m];
    sC[i] = Cb[d * 256 + nt + m];
  }
  __syncthreads();
  if (threadIdx.x < 64) {
    int j = threadIdx.x;
    float a = 0.f, c2 = 0.f;
    for (int d = 0; d < 64; ++d) {
      a += swb[64 + d] * sC[d * 64 + j];
      c2 += swb[d] * sQ[d * 64 + j];
    }
    ct[j] = a; qt[j] = c2;
  }
  __syncthreads();
  int m = threadIdx.x & 63, wv = threadIdx.x >> 6;
  for (int it = 0; it < 16; ++it) {
    int nl = wv + it * 4;
    float acc = ct[nl] + qt[m];
    for (int d = 0; d < 64; ++d)
      acc += sC[d * 64 + nl] * swb[128 + d] * sQ[d * 64 + m];
    S[((size_t)b * 256 + nt + nl) * 64 + m] = acc;
    float mx = acc;
#pragma unroll
    for (int o = 32; o > 0; o >>= 1) mx = fmaxf(mx, __shfl_xor(mx, o));
    float p = __expf(acc - mx);
#pragma unroll
    for (int o = 32; o > 0; o >>= 1) p += __shfl_xor(p, o);
    if (m == 0) { rmax[b * 256 + nt + nl] = mx; rsum[b * 256 + nt + nl] = p; }
  }
}

__global__ void k_cqcol(const float* __restrict__ S, float* __restrict__ cmax,
                        float* __restrict__ csum) {
  int b = blockIdx.x, m = threadIdx.x;
  const float* Sb = S + (size_t)b * 256 * 64;
  float mx = -1e30f;
  for (int n = 0; n < 256; ++n) mx = fmaxf(mx, Sb[n * 64 + m]);
  float s = 0.f;
  for (int n = 0; n < 256; ++n) s += __expf(Sb[n * 64 + m] - mx);
  cmax[b * 64 + m] = mx; csum[b * 64 + m] = s;
}

__global__ __launch_bounds__(256) void k_cqA(
    const float* __restrict__ C, const float* __restrict__ Q,
    const float* __restrict__ S, const float* __restrict__ rmax,
    const float* __restrict__ rsum, float* __restrict__ Xcat) {
  int b = blockIdx.x, nt = blockIdx.y * 64;
  __shared__ float sQ[4096];
  __shared__ float sP[64 * 65];
  const float* Qb = Q + (size_t)b * 4096;
  for (int i = threadIdx.x; i < 4096; i += 256) sQ[i] = Qb[i];
  for (int i = threadIdx.x; i < 4096; i += 256) {
    int nl = i >> 6, m = i & 63;
    int n = nt + nl;
    sP[nl * 65 + m] = __expf(S[((size_t)b * 256 + n) * 64 + m] - rmax[b * 256 + n]) / rsum[b * 256 + n];
  }
  __syncthreads();
  int nl = threadIdx.x & 63, dg = threadIdx.x >> 6;
  int n = nt + nl;
  for (int j = 0; j < 16; ++j) {
    int d = dg * 16 + j;
    float acc = 0.f;
    for (int m = 0; m < 64; ++m) acc += sQ[d * 64 + m] * sP[nl * 65 + m];
    float cv = C[((size_t)b * 64 + d) * 256 + n];
    Xcat[((size_t)b * 256 + d) * 256 + n] = cv;
    Xcat[((size_t)b * 256 + 64 + d) * 256 + n] = acc;
    Xcat[((size_t)b * 256 + 128 + d) * 256 + n] = cv * acc;
  }
}

// CS2[d,m] = sum_n C[d,n] * S2[n,m]
__global__ __launch_bounds__(256) void k_cqCS2(
    const float* __restrict__ C, const float* __restrict__ S,
    const float* __restrict__ cmax, const float* __restrict__ csum,
    float* __restrict__ CS2) {
  int b = blockIdx.x;
  __shared__ float sP[4096], sC[4096];
  int m = threadIdx.x & 63, dg = threadIdx.x >> 6;
  float acc[16];
#pragma unroll
  for (int j = 0; j < 16; ++j) acc[j] = 0.f;
  for (int nt = 0; nt < 4; ++nt) {
    __syncthreads();
    for (int i = threadIdx.x; i < 4096; i += 256) {
      int nl = i >> 6, mm = i & 63;
      int n = nt * 64 + nl;
      sP[i] = __expf(S[((size_t)b * 256 + n) * 64 + mm] - cmax[b * 64 + mm]) / csum[b * 64 + mm];
      int d = i >> 6, nn = i & 63;
      sC[i] = C[((size_t)b * 64 + d) * 256 + nt * 64 + nn];
    }
    __syncthreads();
    for (int nl = 0; nl < 64; ++nl) {
      float p = sP[nl * 64 + m];
#pragma unroll
      for (int j = 0; j < 16; ++j) acc[j] += sC[(dg * 16 + j) * 64 + nl] * p;
    }
  }
  for (int j = 0; j < 16; ++j)
    CS2[((size_t)b * 64 + dg * 16 + j) * 64 + m] = acc[j];
}

// Bm[d,k] = sum_m CS2[d,m] * S1[k,m]
__global__ __launch_bounds__(256) void k_cqBm(
    const float* __restrict__ C, const float* __restrict__ CS2,
    const float* __restrict__ S, const float* __restrict__ rmax,
    const float* __restrict__ rsum, float* __restrict__ Xcat) {
  int b = blockIdx.x, kt = blockIdx.y * 64;
  __shared__ float sW[4096];
  __shared__ float sP[64 * 65];
  for (int i = threadIdx.x; i < 4096; i += 256) sW[i] = CS2[(size_t)b * 4096 + i];
  for (int i = threadIdx.x; i < 4096; i += 256) {
    int kl = i >> 6, m = i & 63;
    int k = kt + kl;
    sP[kl * 65 + m] = __expf(S[((size_t)b * 256 + k) * 64 + m] - rmax[b * 256 + k]) / rsum[b * 256 + k];
  }
  __syncthreads();
  int kl = threadIdx.x & 63, dg = threadIdx.x >> 6;
  int k = kt + kl;
  for (int j = 0; j < 16; ++j) {
    int d = dg * 16 + j;
    float acc = 0.f;
    for (int m = 0; m < 64; ++m) acc += sW[d * 64 + m] * sP[kl * 65 + m];
    float cv = C[((size_t)b * 64 + d) * 256 + k];
    Xcat[((size_t)b * 256 + 192 + d) * 256 + k] = cv * acc;
  }
}

// ---- both pointers in one launch: grid (B, 2) ----------------------------
__global__ void k_pointer2(const float* __restrict__ M0, const float* __restrict__ M1,
                           const float* __restrict__ M2, const float* __restrict__ w0,
                           const float* __restrict__ w1, float* __restrict__ out) {
  int b = blockIdx.x, sel = blockIdx.y, n = threadIdx.x;
  const float* wb = (sel ? w1 : w0) + b * 128;
  const float* Mb = sel ? M2 : M1;
  float y = 0.f;
  for (int d = 0; d < 64; ++d) {
    y += wb[d] * M0[((size_t)b * 64 + d) * 256 + n];
    y += wb[64 + d] * Mb[((size_t)b * 64 + d) * 256 + n];
  }
  __shared__ float wred[4], wsum[4];
  int lane = n & 63, wid = n >> 6;
  float mx = y;
#pragma unroll
  for (int o = 32; o > 0; o >>= 1) mx = fmaxf(mx, __shfl_xor(mx, o));
  if (lane == 0) wred[wid] = mx;
  __syncthreads();
  mx = fmaxf(fmaxf(wred[0], wred[1]), fmaxf(wred[2], wred[3]));
  float e = __expf(y - mx);
  float s = e;
#pragma unroll
  for (int o = 32; o > 0; o >>= 1) s += __shfl_xor(s, o);
  if (lane == 0) wsum[wid] = s;
  __syncthreads();
  s = wsum[0] + wsum[1] + wsum[2] + wsum[3];
  out[sel * 6144 + b * 256 + n] = e / s;
}

// ===========================================================================
extern "C" void kernel_launch(void* const* d_in, const int* in_sizes, int n_in,
                              void* d_out, int out_size, void* d_ws, size_t ws_size,
                              hipStream_t stream) {
  const float* word_table = (const float*)d_in[0];
  const float* char_table = (const float*)d_in[1];
  const float* e2dw = (const float*)d_in[2];
  const float* e2db = (const float*)d_in[3];
  const float* e2pw = (const float*)d_in[4];
  const float* e2pb = (const float*)d_in[5];
  const float* e1dw = (const float*)d_in[6];
  const float* e1db = (const float*)d_in[7];
  const float* e1pw = (const float*)d_in[8];
  const float* e1pb = (const float*)d_in[9];
  const float* hlw = (const float*)d_in[10];
  const float* hlb = (const float*)d_in[11];
  const float* hgw = (const float*)d_in[12];
  const float* hgb = (const float*)d_in[13];
  const float *enc_dw[5], *enc_pw[5], *enc_wq[5], *enc_wk[5], *enc_wv[5], *enc_wo[5], *enc_w[5];
  for (int p = 0; p < 5; ++p) {
    enc_dw[p] = (const float*)d_in[14 + 7 * p + 0];
    enc_pw[p] = (const float*)d_in[14 + 7 * p + 1];
    enc_wq[p] = (const float*)d_in[14 + 7 * p + 2];
    enc_wk[p] = (const float*)d_in[14 + 7 * p + 3];
    enc_wv[p] = (const float*)d_in[14 + 7 * p + 4];
    enc_wo[p] = (const float*)d_in[14 + 7 * p + 5];
    enc_w[p]  = (const float*)d_in[14 + 7 * p + 6];
  }
  const float* cq_w  = (const float*)d_in[49];
  const float* rs_dw = (const float*)d_in[50];
  const float* rs_pw = (const float*)d_in[51];
  const float* p_w0  = (const float*)d_in[52];
  const float* p_w1  = (const float*)d_in[53];
  const int* Cwid = (const int*)d_in[54];
  const int* Ccid = (const int*)d_in[55];
  const int* Qwid = (const int*)d_in[56];
  const int* Qcid = (const int*)d_in[57];
  float* out = (float*)d_out;

  // ---- workspace (floats), ~12 MB ----------------------------------------
  float* ws = (float*)d_ws;
  float* postab = ws;                  // 16384
  float* U    = ws + 16384;            // 393216  (att head out)
  float* Xcat = ws + 409600;           // 1572864 ; M2 aliases; emb scratch
  float* CX   = ws + 1982464;          // 393216  ; M0 aliases
  float* Sb   = ws + 2375680;          // 393216  ; M1 aliases
  float* QX   = ws + 2768896;          // 98304
  float* CS2  = ws + 2867200;          // 98304
  float* rmax = ws + 2965504;          // 6144
  float* rsum = ws + 2971648;          // 6144
  float* cmax = ws + 2977792;          // 1536
  float* csum = ws + 2979328;          // 1536
  float* P0   = ws + 2980864;          // 12288
  float* P1   = ws + 2993152;          // 12288  -> ends 3005440
  float* M0 = CX; float* M1 = Sb; float* M2 = Xcat;
  float* E1 = Xcat; float* E2 = Xcat + 393216;  // embedding scratch (pre-cq)
  (void)out_size; (void)in_sizes; (void)n_in; (void)ws_size;

  // encoder block: X += tab; cnum x fconv; att+wo; FF.  src=nullptr => in place
  auto run_enc = [&](float* X, const float* src, int L, int cnum, int K, int p) {
    int NB = B * 64 / 4;
    if (src)
      hipLaunchKernelGGL((k_posadd_stats<true>), dim3(NB), dim3(256), 0, stream, X, src, postab, P0, L);
    else
      hipLaunchKernelGGL((k_posadd_stats<false>), dim3(NB), dim3(256), 0, stream, X, (const float*)nullptr, postab, P0, L);
    float* pin = P0; float* pout = P1;
    for (int i = 0; i < cnum; ++i) {
      if (K == 7)
        hipLaunchKernelGGL((k_fconv<7>), dim3(B, L / 64), dim3(256), 0, stream,
                           X, enc_dw[p] + i * 64 * 7, enc_pw[p] + (size_t)i * 4096, pin, pout, L);
      else
        hipLaunchKernelGGL((k_fconv<5>), dim3(B, L / 64), dim3(256), 0, stream,
                           X, enc_dw[p] + i * 64 * 5, enc_pw[p] + (size_t)i * 4096, pin, pout, L);
      float* t = pin; pin = pout; pout = t;
    }
    // pin now holds stats of current X
    k_att<<<dim3(HH, B), 256, 0, stream>>>(X, pin, enc_wq[p], enc_wk[p], enc_wv[p], U, L);
    // wo: no norm, +res, emit stats into pout
    hipLaunchKernelGGL((k_matmul2<false, false, true>), dim3(B, L / 64), dim3(256), 0, stream,
                       U, enc_wo[p], (const float*)X, X, (const float*)nullptr, pout, L);
    // FF: norm (stats=pout), relu, +res, no stats
    hipLaunchKernelGGL((k_matmul2<true, true, false>), dim3(B, L / 64), dim3(256), 0, stream,
                       X, enc_w[p], (const float*)X, X, pout, (float*)nullptr, L);
  };

  k_postab<<<64, 256, 0, stream>>>(postab);
  // ---- embeddings ----
  k_charembed<<<dim3(NN, B), 256, 0, stream>>>(Ccid, char_table, e2dw, e2db, e2pw, e2pb, E1, NN);
  k_embconv<<<dim3(NN, B), 64, 0, stream>>>(E1, Cwid, word_table, e1dw, e1db, e1pw, e1pb, E2, NN);
  k_highway<<<dim3(NN, B), 64, 0, stream>>>(E2, hlw, hlb, hgw, hgb, CX, NN);
  k_charembed<<<dim3(MQ, B), 256, 0, stream>>>(Qcid, char_table, e2dw, e2db, e2pw, e2pb, E1, MQ);
  k_embconv<<<dim3(MQ, B), 64, 0, stream>>>(E1, Qwid, word_table, e1dw, e1db, e1pw, e1pb, E2, MQ);
  k_highway<<<dim3(MQ, B), 64, 0, stream>>>(E2, hlw, hlb, hgw, hgb, QX, MQ);
  // ---- embedding encoders ----
  run_enc(CX, nullptr, 256, 4, 7, 0);
  run_enc(QX, nullptr, 64, 4, 7, 1);
  // ---- context-query attention ----
  k_cqS<<<dim3(B, 4), 256, 0, stream>>>(CX, QX, cq_w, Sb, rmax, rsum);
  k_cqcol<<<B, 64, 0, stream>>>(Sb, cmax, csum);
  k_cqA<<<dim3(B, 4), 256, 0, stream>>>(CX, QX, Sb, rmax, rsum, Xcat);
  k_cqCS2<<<B, 256, 0, stream>>>(CX, Sb, cmax, csum, CS2);
  k_cqBm<<<dim3(B, 4), 256, 0, stream>>>(CX, CS2, Sb, rmax, rsum, Xcat);
  // ---- resize -> M0 (CX region; CX dead after cq) ----
  k_resize<<<dim3(B, 4), 256, 0, stream>>>(Xcat, rs_dw, rs_pw, M0);
  // ---- model encoders (copy fused into first posadd of each stack) ----
  for (int r = 0; r < 7; ++r) run_enc(M0, nullptr, 256, 2, 5, 2);
  run_enc(M1, M0, 256, 2, 5, 3);
  for (int r = 1; r < 7; ++r) run_enc(M1, nullptr, 256, 2, 5, 3);
  run_enc(M2, M1, 256, 2, 5, 4);
  for (int r = 1; r < 7; ++r) run_enc(M2, nullptr, 256, 2, 5, 4);
  // ---- pointers ----
  k_pointer2<<<dim3(B, 2), 256, 0, stream>>>(M0, M1, M2, p_w0, p_w1, out);
}

// Round 9
// 4543.236 us; speedup vs baseline: 1.0201x; 1.0201x over previous
//
#include <hip/hip_runtime.h>
#include <math.h>

constexpr int B = 24, HH = 8;
constexpr int NN = 256, MQ = 64;
constexpr int EC = 364;

#define PI_2 1.5707963267948966f

// stats partials layout: parts[row][4][2], row = b*64+d
__device__ __forceinline__ void combine_stats(const float* __restrict__ parts,
                                              int row, int NT, float Lf,
                                              float& mu, float& inv) {
  float s = 0.f, q = 0.f;
  for (int t = 0; t < NT; ++t) {
    s += parts[((size_t)row * 4 + t) * 2];
    q += parts[((size_t)row * 4 + t) * 2 + 1];
  }
  mu = s / Lf;
  float var = (q - s * mu) / (Lf - 1.f);
  if (var < 0.f) var = 0.f;
  inv = 1.f / (sqrtf(var) + 1e-6f);
}

// ---------------- positional encoding table: tab[d*256+l] ----------------
__global__ void k_postab(float* __restrict__ tab) {
  int d = blockIdx.x, l = threadIdx.x;
  float fr = ((d & 1) == 0) ? powf(10000.f, -(float)d / 64.f)
                            : -powf(10000.f, -(float)(d - 1) / 64.f);
  float ph = (d & 1) ? PI_2 : 0.f;
  tab[d * 256 + l] = sinf(sinf((float)l * fr + ph));
}

// ---- X = (COPY? src : X) + tab ; emit per-tile row stats -----------------
template<bool COPY>
__global__ void k_posadd_stats(float* __restrict__ X, const float* __restrict__ src,
                               const float* __restrict__ tab, float* __restrict__ parts,
                               int L) {
  int row = blockIdx.x * 4 + (threadIdx.x >> 6);
  int lane = threadIdx.x & 63;
  int d = row & 63;
  float* xr = X + (size_t)row * L;
  const float* sr = COPY ? (src + (size_t)row * L) : xr;
  int NT = L >> 6;
  for (int t = 0; t < NT; ++t) {
    int l = t * 64 + lane;
    float v = sr[l] + tab[d * 256 + l];
    xr[l] = v;
    float s = v, q = v * v;
#pragma unroll
    for (int o = 32; o > 0; o >>= 1) { s += __shfl_xor(s, o); q += __shfl_xor(q, o); }
    if (lane == 0) {
      parts[((size_t)row * 4 + t) * 2] = s;
      parts[((size_t)row * 4 + t) * 2 + 1] = q;
    }
  }
}

// ---- fused: normalize -> dwconv(K) -> pw matmul -> relu -> +res -> X -----
template<int K>
__global__ __launch_bounds__(256) void k_fconv(
    float* __restrict__ X, const float* __restrict__ dw, const float* __restrict__ pw,
    const float* __restrict__ partsIn, float* __restrict__ partsOut, int L) {
  constexpr int H = K / 2, SW = 64 + 2 * H;
  __shared__ float smu[64], sinv[64];
  __shared__ float sN[64 * SW];
  __shared__ float sD[64 * 65];
  __shared__ float sWt[4096];
  int b = blockIdx.x, lt = blockIdx.y * 64;
  int tid = threadIdx.x;
  int NT = L >> 6;
  if (tid < 64) combine_stats(partsIn, b * 64 + tid, NT, (float)L, smu[tid], sinv[tid]);
  for (int i = tid; i < 4096; i += 256) sWt[i] = pw[i];
  __syncthreads();
  float* Xb = X + (size_t)b * 64 * L;
  for (int i = tid; i < 64 * SW; i += 256) {
    int c = i / SW, jj = i % SW;
    int gl = lt + jj - H;
    sN[i] = (gl >= 0 && gl < L) ? (Xb[(size_t)c * L + gl] - smu[c]) * sinv[c] : 0.f;
  }
  __syncthreads();
  for (int i = tid; i < 4096; i += 256) {
    int c = i >> 6, l = i & 63;
    float acc = 0.f;
#pragma unroll
    for (int k = 0; k < K; ++k) acc += sN[c * SW + l + k] * dw[c * K + k];
    sD[c * 65 + l] = acc;
  }
  __syncthreads();
  int l = tid & 63, og = tid >> 6;
  float acc[16];
#pragma unroll
  for (int j = 0; j < 16; ++j) acc[j] = 0.f;
  for (int c = 0; c < 64; ++c) {
    float av = sD[c * 65 + l];
#pragma unroll
    for (int j = 0; j < 16; ++j) acc[j] += sWt[(og * 16 + j) * 64 + c] * av;
  }
  __syncthreads();
#pragma unroll
  for (int j = 0; j < 16; ++j) {
    int o = og * 16 + j;
    float v = Xb[(size_t)o * L + lt + l] + fmaxf(acc[j], 0.f);
    Xb[(size_t)o * L + lt + l] = v;
    sD[o * 65 + l] = v;
  }
  __syncthreads();
  if (tid < 64) {
    int o = tid;
    float s = 0.f, q = 0.f;
    for (int l2 = 0; l2 < 64; ++l2) { float v = sD[o * 65 + l2]; s += v; q += v * v; }
    partsOut[((size_t)(b * 64 + o) * 4 + blockIdx.y) * 2] = s;
    partsOut[((size_t)(b * 64 + o) * 4 + blockIdx.y) * 2 + 1] = q;
  }
}

// ---- generic 64x64 matmul: out = res + act(W . (norm?)A) ; opt stats -----
template<bool NORM, bool RELU, bool STATS>
__global__ __launch_bounds__(256) void k_matmul2(
    const float* __restrict__ A, const float* __restrict__ W,
    const float* __restrict__ res, float* __restrict__ out,
    const float* __restrict__ partsIn, float* __restrict__ partsOut, int L) {
  __shared__ float sA[64 * 65];
  __shared__ float sW[4096];
  __shared__ float smu[64], sinv[64];
  int b = blockIdx.x, lt = blockIdx.y * 64;
  int tid = threadIdx.x;
  int NT = L >> 6;
  if (NORM && tid < 64) combine_stats(partsIn, b * 64 + tid, NT, (float)L, smu[tid], sinv[tid]);
  const float* Wb = W + (size_t)b * 4096;
  for (int i = tid; i < 4096; i += 256) sW[i] = Wb[i];
  if (NORM) __syncthreads();
  const float* Ab = A + (size_t)b * 64 * L;
  for (int i = tid; i < 4096; i += 256) {
    int c = i >> 6, ll = i & 63;
    float v = Ab[(size_t)c * L + lt + ll];
    if (NORM) v = (v - smu[c]) * sinv[c];
    sA[c * 65 + ll] = v;
  }
  __syncthreads();
  int l = tid & 63, og = tid >> 6;
  float acc[16];
#pragma unroll
  for (int j = 0; j < 16; ++j) acc[j] = 0.f;
  for (int c = 0; c < 64; ++c) {
    float av = sA[c * 65 + l];
#pragma unroll
    for (int j = 0; j < 16; ++j) acc[j] += sW[(og * 16 + j) * 64 + c] * av;
  }
  if (STATS) __syncthreads();
#pragma unroll
  for (int j = 0; j < 16; ++j) {
    int o = og * 16 + j;
    float v = acc[j];
    if (RELU) v = fmaxf(v, 0.f);
    size_t idx = ((size_t)b * 64 + o) * L + lt + l;
    v += res[idx];
    out[idx] = v;
    if (STATS) sA[o * 65 + l] = v;
  }
  if (STATS) {
    __syncthreads();
    if (tid < 64) {
      int o = tid;
      float s = 0.f, q = 0.f;
      for (int l2 = 0; l2 < 64; ++l2) { float v = sA[o * 65 + l2]; s += v; q += v * v; }
      partsOut[((size_t)(b * 64 + o) * 4 + blockIdx.y) * 2] = s;
      partsOut[((size_t)(b * 64 + o) * 4 + blockIdx.y) * 2 + 1] = q;
    }
  }
}

// ---- fused resize: M0[b,o,l] = sum_c pw[o,c] * dw5(Xcat)[b,c,l] ----------
__global__ __launch_bounds__(256) void k_resize(
    const float* __restrict__ Xcat, const float* __restrict__ dw,
    const float* __restrict__ pw, float* __restrict__ out) {
  __shared__ float sA[64 * 64];
  int b = blockIdx.x, lt = blockIdx.y * 64;
  int l = threadIdx.x & 63, og = threadIdx.x >> 6;
  float acc[16];
#pragma unroll
  for (int j = 0; j < 16; ++j) acc[j] = 0.f;
  for (int c0 = 0; c0 < 256; c0 += 64) {
    __syncthreads();
    for (int i = threadIdx.x; i < 4096; i += 256) {
      int c = (i >> 6) + c0, ll = (i & 63) + lt;
      const float* xr = Xcat + ((size_t)b * 256 + c) * 256;
      float a = 0.f;
#pragma unroll
      for (int k = 0; k < 5; ++k) {
        int p = ll + k - 2;
        if (p >= 0 && p < 256) a += xr[p] * dw[c * 5 + k];
      }
      sA[i] = a;
    }
    __syncthreads();
    for (int c = 0; c < 64; ++c) {
      float av = sA[c * 64 + l];
#pragma unroll
      for (int j = 0; j < 16; ++j)
        acc[j] += pw[(size_t)(og * 16 + j) * 256 + c0 + c] * av;
    }
  }
#pragma unroll
  for (int j = 0; j < 16; ++j)
    out[((size_t)b * 64 + og * 16 + j) * 256 + lt + l] = acc[j];
}

// ---- self-attention with inline norm, online softmax ---------------------
__global__ __launch_bounds__(256) void k_att(
    const float* __restrict__ X, const float* __restrict__ partsIn,
    const float* __restrict__ wq, const float* __restrict__ wk,
    const float* __restrict__ wv, float* __restrict__ hc, int L) {
  int h = blockIdx.x, b = blockIdx.y;
  __shared__ float smu[64], sinv[64];
  __shared__ float sX[64 * 65];
  __shared__ float sQ[8 * 256], sK8[8 * 256], sV[8 * 256];
  __shared__ float swq[512], swk[512], swv[512];
  int tid = threadIdx.x;
  int NT = L >> 6;
  if (tid < 64) combine_stats(partsIn, b * 64 + tid, NT, (float)L, smu[tid], sinv[tid]);
  size_t woff = (size_t)(h * B + b) * 512;
  for (int i = tid; i < 512; i += 256) {
    swq[i] = wq[woff + i]; swk[i] = wk[woff + i]; swv[i] = wv[woff + i];
  }
  __syncthreads();
  const float* Xb = X + (size_t)b * 64 * L;
  for (int lt = 0; lt < L; lt += 64) {
    for (int i = tid; i < 4096; i += 256) {
      int d = i >> 6, l = i & 63;
      sX[d * 65 + l] = (Xb[(size_t)d * L + lt + l] - smu[d]) * sinv[d];
    }
    __syncthreads();
    for (int i = tid; i < 512; i += 256) {
      int k = i >> 6, l = i & 63;
      float aq = 0.f, ak = 0.f, av = 0.f;
      for (int d = 0; d < 64; ++d) {
        float x = sX[d * 65 + l];
        aq += swq[k * 64 + d] * x;
        ak += swk[k * 64 + d] * x;
        av += swv[k * 64 + d] * x;
      }
      sQ[k * L + lt + l] = aq; sK8[k * L + lt + l] = ak; sV[k * L + lt + l] = av;
    }
    __syncthreads();
  }
  const float scale = 0.35355339059327373f;  // 1/sqrt(8)
  for (int m = tid; m < L; m += 256) {
    float kc[8];
#pragma unroll
    for (int k = 0; k < 8; ++k) kc[k] = sK8[k * L + m];
    float mx = -1e30f, sum = 0.f, acc[8];
#pragma unroll
    for (int v = 0; v < 8; ++v) acc[v] = 0.f;
    for (int l = 0; l < L; ++l) {
      float s = 0.f;
#pragma unroll
      for (int k = 0; k < 8; ++k) s += sQ[k * L + l] * kc[k];
      s *= scale;
      if (s <= mx) {
        float p = __expf(s - mx);
        sum += p;
#pragma unroll
        for (int v = 0; v < 8; ++v) acc[v] += p * sV[v * L + l];
      } else {
        float corr = __expf(mx - s);
        sum = sum * corr + 1.f;
#pragma unroll
        for (int v = 0; v < 8; ++v) acc[v] = acc[v] * corr + sV[v * L + l];
        mx = s;
      }
    }
    float is = 1.f / sum;
    for (int v = 0; v < 8; ++v)
      hc[((size_t)b * 64 + h * 8 + v) * L + m] = acc[v] * is;
  }
}

// ---- fused char embed: COALESCED gather (ce contiguous per wave) ---------
__global__ __launch_bounds__(256) void k_charembed(
    const int* __restrict__ cid, const float* __restrict__ ctab,
    const float* __restrict__ dw, const float* __restrict__ db,
    const float* __restrict__ pw, const float* __restrict__ pb,
    float* __restrict__ out, int Ln) {
  int n = blockIdx.x, b = blockIdx.y;
  __shared__ float dwo[16 * 200];   // [cn][ce]
  __shared__ int sid[5][16];
  __shared__ float red[256];
  int tid = threadIdx.x;
  if (tid < 80) {
    int kn = tid / 16, cn = tid % 16;
    int nn = n + kn - 2;
    sid[kn][cn] = (nn >= 0 && nn < Ln) ? cid[((size_t)b * Ln + nn) * 16 + cn] : -1;
  }
  __syncthreads();
  // i -> cn = i/200, ce = i%200 : lanes share id, read consecutive ctab addrs
  for (int i = tid; i < 16 * 200; i += 256) {
    int cn = i / 200, ce = i % 200;
    float acc = db[ce];
    const float* wcc = dw + ce * 25;
#pragma unroll
    for (int kn = 0; kn < 5; ++kn) {
#pragma unroll
      for (int kc = 0; kc < 5; ++kc) {
        int cc = cn + kc - 2;
        if (cc < 0 || cc >= 16) continue;
        int id = sid[kn][cc];
        if (id >= 0) acc += ctab[(size_t)id * 200 + ce] * wcc[kn * 5 + kc];
      }
    }
    dwo[cn * 200 + ce] = acc;
  }
  __syncthreads();
  int o = tid & 63, q = tid >> 6;
  float mx = -1e30f;
  const float* pwr = pw + o * 200;
  for (int cn = q; cn < 16; cn += 4) {
    float acc = pb[o];
    const float* dr = dwo + cn * 200;
    for (int ce = 0; ce < 200; ++ce) acc += pwr[ce] * dr[ce];
    mx = fmaxf(mx, acc);
  }
  red[tid] = mx;
  __syncthreads();
  if (q == 0) {
    mx = fmaxf(fmaxf(red[o], red[64 + o]), fmaxf(red[128 + o], red[192 + o]));
    out[((size_t)b * 64 + o) * Ln + n] = fmaxf(mx, 0.f);
  }
}

// ---- fused emb conv ------------------------------------------------------
__global__ void k_embconv(const float* __restrict__ chx, const int* __restrict__ wid,
                          const float* __restrict__ wtab, const float* __restrict__ dw,
                          const float* __restrict__ db, const float* __restrict__ pw,
                          const float* __restrict__ pb, float* __restrict__ out, int Ln) {
  int n = blockIdx.x, b = blockIdx.y;
  __shared__ float dwc[EC];
  __shared__ int sw[5];
  int tid = threadIdx.x;
  if (tid < 5) {
    int nn = n + tid - 2;
    sw[tid] = (nn >= 0 && nn < Ln) ? wid[(size_t)b * Ln + nn] : -1;
  }
  __syncthreads();
  for (int ch = tid; ch < EC; ch += 64) {
    float acc = db[ch];
#pragma unroll
    for (int k = 0; k < 5; ++k) {
      int nn = n + k - 2;
      float v = 0.f;
      if (nn >= 0 && nn < Ln) {
        if (ch < 64) v = chx[((size_t)b * 64 + ch) * Ln + nn];
        else v = wtab[(size_t)sw[k] * 300 + (ch - 64)];
      }
      acc += v * dw[ch * 5 + k];
    }
    dwc[ch] = acc;
  }
  __syncthreads();
  int o = tid;
  float acc = pb[o];
  const float* pwr = pw + o * EC;
  for (int c = 0; c < EC; ++c) acc += pwr[c] * dwc[c];
  out[((size_t)b * 64 + o) * Ln + n] = acc;
}

// ---------------- highway -------------------------------------------------
__global__ void k_highway(const float* __restrict__ inx, const float* __restrict__ lw,
                          const float* __restrict__ lb, const float* __restrict__ gw,
                          const float* __restrict__ gb, float* __restrict__ out, int Ln) {
  int n = blockIdx.x, b = blockIdx.y;
  __shared__ float x[64], xn[64];
  int o = threadIdx.x;
  x[o] = inx[((size_t)b * 64 + o) * Ln + n];
  __syncthreads();
  for (int layer = 0; layer < 2; ++layer) {
    const float* lwr = lw + (layer * 64 + o) * 64;
    const float* gwr = gw + (layer * 64 + o) * 64;
    float gl = gb[layer * 64 + o], nl = lb[layer * 64 + o];
    for (int d = 0; d < 64; ++d) { gl += gwr[d] * x[d]; nl += lwr[d] * x[d]; }
    float g = 1.f / (1.f + __expf(-gl));
    float r = fmaxf(nl, 0.f);
    xn[o] = g * r + (1.f - g) * x[o];
    __syncthreads();
    x[o] = xn[o];
    __syncthreads();
  }
  out[((size_t)b * 64 + o) * Ln + n] = x[o];
}

// ---------------- context-query attention ---------------------------------
__global__ __launch_bounds__(256) void k_cqS(const float* __restrict__ C,
                                             const float* __restrict__ Q,
                                             const float* __restrict__ w,
                                             float* __restrict__ S,
                                             float* __restrict__ rmax,
                                             float* __restrict__ rsum) {
  int b = blockIdx.x, nt = blockIdx.y * 64;
  __shared__ float sQ[4096], sC[4096], ct[64], qt[64], swb[192];
  const float* Cb = C + (size_t)b * 64 * 256;
  const float* Qb = Q + (size_t)b * 4096;
  const float* wb = w + (size_t)b * 192;
  if (threadIdx.x < 192) swb[threadIdx.x] = wb[threadIdx.x];
  for (int i = threadIdx.x; i < 4096; i += 256) {
    int d = i >> 6, m = i & 63;
    sQ[i] = Qb[d * 64 + m];
    sC[i] = Cb[d * 256 + nt + m];
  }
  __syncthreads();
  if (threadIdx.x < 64) {
    int j = threadIdx.x;
    float a = 0.f, c2 = 0.f;
    for (int d = 0; d < 64; ++d) {
      a += swb[64 + d] * sC[d * 64 + j];
      c2 += swb[d] * sQ[d * 64 + j];
    }
    ct[j] = a; qt[j] = c2;
  }
  __syncthreads();
  int m = threadIdx.x & 63, wv = threadIdx.x >> 6;
  for (int it = 0; it < 16; ++it) {
    int nl = wv + it * 4;
    float acc = ct[nl] + qt[m];
    for (int d = 0; d < 64; ++d)
      acc += sC[d * 64 + nl] * swb[128 + d] * sQ[d * 64 + m];
    S[((size_t)b * 256 + nt + nl) * 64 + m] = acc;
    float mx = acc;
#pragma unroll
    for (int o = 32; o > 0; o >>= 1) mx = fmaxf(mx, __shfl_xor(mx, o));
    float p = __expf(acc - mx);
#pragma unroll
    for (int o = 32; o > 0; o >>= 1) p += __shfl_xor(p, o);
    if (m == 0) { rmax[b * 256 + nt + nl] = mx; rsum[b * 256 + nt + nl] = p; }
  }
}

__global__ void k_cqcol(const float* __restrict__ S, float* __restrict__ cmax,
                        float* __restrict__ csum) {
  int b = blockIdx.x, m = threadIdx.x;
  const float* Sb = S + (size_t)b * 256 * 64;
  float mx = -1e30f;
  for (int n = 0; n < 256; ++n) mx = fmaxf(mx, Sb[n * 64 + m]);
  float s = 0.f;
  for (int n = 0; n < 256; ++n) s += __expf(Sb[n * 64 + m] - mx);
  cmax[b * 64 + m] = mx; csum[b * 64 + m] = s;
}

__global__ __launch_bounds__(256) void k_cqA(
    const float* __restrict__ C, const float* __restrict__ Q,
    const float* __restrict__ S, const float* __restrict__ rmax,
    const float* __restrict__ rsum, float* __restrict__ Xcat) {
  int b = blockIdx.x, nt = blockIdx.y * 64;
  __shared__ float sQ[4096];
  __shared__ float sP[64 * 65];
  const float* Qb = Q + (size_t)b * 4096;
  for (int i = threadIdx.x; i < 4096; i += 256) sQ[i] = Qb[i];
  for (int i = threadIdx.x; i < 4096; i += 256) {
    int nl = i >> 6, m = i & 63;
    int n = nt + nl;
    sP[nl * 65 + m] = __expf(S[((size_t)b * 256 + n) * 64 + m] - rmax[b * 256 + n]) / rsum[b * 256 + n];
  }
  __syncthreads();
  int nl = threadIdx.x & 63, dg = threadIdx.x >> 6;
  int n = nt + nl;
  for (int j = 0; j < 16; ++j) {
    int d = dg * 16 + j;
    float acc = 0.f;
    for (int m = 0; m < 64; ++m) acc += sQ[d * 64 + m] * sP[nl * 65 + m];
    float cv = C[((size_t)b * 64 + d) * 256 + n];
    Xcat[((size_t)b * 256 + d) * 256 + n] = cv;
    Xcat[((size_t)b * 256 + 64 + d) * 256 + n] = acc;
    Xcat[((size_t)b * 256 + 128 + d) * 256 + n] = cv * acc;
  }
}

// CS2[d,m] = sum_n C[d,n] * S2[n,m]
__global__ __launch_bounds__(256) void k_cqCS2(
    const float* __restrict__ C, const float* __restrict__ S,
    const float* __restrict__ cmax, const float* __restrict__ csum,
    float* __restrict__ CS2) {
  int b = blockIdx.x;
  __shared__ float sP[4096], sC[4096];
  int m = threadIdx.x & 63, dg = threadIdx.x >> 6;
  float acc[16];
#pragma unroll
  for (int j = 0; j < 16; ++j) acc[j] = 0.f;
  for (int nt = 0; nt < 4; ++nt) {
    __syncthreads();
    for (int i = threadIdx.x; i < 4096; i += 256) {
      int nl = i >> 6, mm = i & 63;
      int n = nt * 64 + nl;
      sP[i] = __expf(S[((size_t)b * 256 + n) * 64 + mm] - cmax[b * 64 + mm]) / csum[b * 64 + mm];
      int d = i >> 6, nn = i & 63;
      sC[i] = C[((size_t)b * 64 + d) * 256 + nt * 64 + nn];
    }
    __syncthreads();
    for (int nl = 0; nl < 64; ++nl) {
      float p = sP[nl * 64 + m];
#pragma unroll
      for (int j = 0; j < 16; ++j) acc[j] += sC[(dg * 16 + j) * 64 + nl] * p;
    }
  }
  for (int j = 0; j < 16; ++j)
    CS2[((size_t)b * 64 + dg * 16 + j) * 64 + m] = acc[j];
}

// Bm[d,k] = sum_m CS2[d,m] * S1[k,m]
__global__ __launch_bounds__(256) void k_cqBm(
    const float* __restrict__ C, const float* __restrict__ CS2,
    const float* __restrict__ S, const float* __restrict__ rmax,
    const float* __restrict__ rsum, float* __restrict__ Xcat) {
  int b = blockIdx.x, kt = blockIdx.y * 64;
  __shared__ float sW[4096];
  __shared__ float sP[64 * 65];
  for (int i = threadIdx.x; i < 4096; i += 256) sW[i] = CS2[(size_t)b * 4096 + i];
  for (int i = threadIdx.x; i < 4096; i += 256) {
    int kl = i >> 6, m = i & 63;
    int k = kt + kl;
    sP[kl * 65 + m] = __expf(S[((size_t)b * 256 + k) * 64 + m] - rmax[b * 256 + k]) / rsum[b * 256 + k];
  }
  __syncthreads();
  int kl = threadIdx.x & 63, dg = threadIdx.x >> 6;
  int k = kt + kl;
  for (int j = 0; j < 16; ++j) {
    int d = dg * 16 + j;
    float acc = 0.f;
    for (int m = 0; m < 64; ++m) acc += sW[d * 64 + m] * sP[kl * 65 + m];
    float cv = C[((size_t)b * 64 + d) * 256 + k];
    Xcat[((size_t)b * 256 + 192 + d) * 256 + k] = cv * acc;
  }
}

// ---- both pointers in one launch: grid (B, 2) ----------------------------
__global__ void k_pointer2(const float* __restrict__ M0, const float* __restrict__ M1,
                           const float* __restrict__ M2, const float* __restrict__ w0,
                           const float* __restrict__ w1, float* __restrict__ out) {
  int b = blockIdx.x, sel = blockIdx.y, n = threadIdx.x;
  const float* wb = (sel ? w1 : w0) + b * 128;
  const float* Mb = sel ? M2 : M1;
  float y = 0.f;
  for (int d = 0; d < 64; ++d) {
    y += wb[d] * M0[((size_t)b * 64 + d) * 256 + n];
    y += wb[64 + d] * Mb[((size_t)b * 64 + d) * 256 + n];
  }
  __shared__ float wred[4], wsum[4];
  int lane = n & 63, wid = n >> 6;
  float mx = y;
#pragma unroll
  for (int o = 32; o > 0; o >>= 1) mx = fmaxf(mx, __shfl_xor(mx, o));
  if (lane == 0) wred[wid] = mx;
  __syncthreads();
  mx = fmaxf(fmaxf(wred[0], wred[1]), fmaxf(wred[2], wred[3]));
  float e = __expf(y - mx);
  float s = e;
#pragma unroll
  for (int o = 32; o > 0; o >>= 1) s += __shfl_xor(s, o);
  if (lane == 0) wsum[wid] = s;
  __syncthreads();
  s = wsum[0] + wsum[1] + wsum[2] + wsum[3];
  out[sel * 6144 + b * 256 + n] = e / s;
}

// ===========================================================================
extern "C" void kernel_launch(void* const* d_in, const int* in_sizes, int n_in,
                              void* d_out, int out_size, void* d_ws, size_t ws_size,
                              hipStream_t stream) {
  const float* word_table = (const float*)d_in[0];
  const float* char_table = (const float*)d_in[1];
  const float* e2dw = (const float*)d_in[2];
  const float* e2db = (const float*)d_in[3];
  const float* e2pw = (const float*)d_in[4];
  const float* e2pb = (const float*)d_in[5];
  const float* e1dw = (const float*)d_in[6];
  const float* e1db = (const float*)d_in[7];
  const float* e1pw = (const float*)d_in[8];
  const float* e1pb = (const float*)d_in[9];
  const float* hlw = (const float*)d_in[10];
  const float* hlb = (const float*)d_in[11];
  const float* hgw = (const float*)d_in[12];
  const float* hgb = (const float*)d_in[13];
  const float *enc_dw[5], *enc_pw[5], *enc_wq[5], *enc_wk[5], *enc_wv[5], *enc_wo[5], *enc_w[5];
  for (int p = 0; p < 5; ++p) {
    enc_dw[p] = (const float*)d_in[14 + 7 * p + 0];
    enc_pw[p] = (const float*)d_in[14 + 7 * p + 1];
    enc_wq[p] = (const float*)d_in[14 + 7 * p + 2];
    enc_wk[p] = (const float*)d_in[14 + 7 * p + 3];
    enc_wv[p] = (const float*)d_in[14 + 7 * p + 4];
    enc_wo[p] = (const float*)d_in[14 + 7 * p + 5];
    enc_w[p]  = (const float*)d_in[14 + 7 * p + 6];
  }
  const float* cq_w  = (const float*)d_in[49];
  const float* rs_dw = (const float*)d_in[50];
  const float* rs_pw = (const float*)d_in[51];
  const float* p_w0  = (const float*)d_in[52];
  const float* p_w1  = (const float*)d_in[53];
  const int* Cwid = (const int*)d_in[54];
  const int* Ccid = (const int*)d_in[55];
  const int* Qwid = (const int*)d_in[56];
  const int* Qcid = (const int*)d_in[57];
  float* out = (float*)d_out;

  // ---- workspace (floats), ~12 MB ----------------------------------------
  float* ws = (float*)d_ws;
  float* postab = ws;                  // 16384
  float* U    = ws + 16384;            // 393216  (att head out)
  float* Xcat = ws + 409600;           // 1572864 ; M2 aliases; emb scratch
  float* CX   = ws + 1982464;          // 393216  ; M0 aliases
  float* Sb   = ws + 2375680;          // 393216  ; M1 aliases
  float* QX   = ws + 2768896;          // 98304
  float* CS2  = ws + 2867200;          // 98304
  float* rmax = ws + 2965504;          // 6144
  float* rsum = ws + 2971648;          // 6144
  float* cmax = ws + 2977792;          // 1536
  float* csum = ws + 2979328;          // 1536
  float* P0   = ws + 2980864;          // 12288
  float* P1   = ws + 2993152;          // 12288  -> ends 3005440
  float* M0 = CX; float* M1 = Sb; float* M2 = Xcat;
  float* E1 = Xcat; float* E2 = Xcat + 393216;  // embedding scratch (pre-cq)
  (void)out_size; (void)in_sizes; (void)n_in; (void)ws_size;

  auto run_enc = [&](float* X, const float* src, int L, int cnum, int K, int p) {
    int NB = B * 64 / 4;
    if (src)
      hipLaunchKernelGGL((k_posadd_stats<true>), dim3(NB), dim3(256), 0, stream, X, src, postab, P0, L);
    else
      hipLaunchKernelGGL((k_posadd_stats<false>), dim3(NB), dim3(256), 0, stream, X, (const float*)nullptr, postab, P0, L);
    float* pin = P0; float* pout = P1;
    for (int i = 0; i < cnum; ++i) {
      if (K == 7)
        hipLaunchKernelGGL((k_fconv<7>), dim3(B, L / 64), dim3(256), 0, stream,
                           X, enc_dw[p] + i * 64 * 7, enc_pw[p] + (size_t)i * 4096, pin, pout, L);
      else
        hipLaunchKernelGGL((k_fconv<5>), dim3(B, L / 64), dim3(256), 0, stream,
                           X, enc_dw[p] + i * 64 * 5, enc_pw[p] + (size_t)i * 4096, pin, pout, L);
      float* t = pin; pin = pout; pout = t;
    }
    k_att<<<dim3(HH, B), 256, 0, stream>>>(X, pin, enc_wq[p], enc_wk[p], enc_wv[p], U, L);
    hipLaunchKernelGGL((k_matmul2<false, false, true>), dim3(B, L / 64), dim3(256), 0, stream,
                       U, enc_wo[p], (const float*)X, X, (const float*)nullptr, pout, L);
    hipLaunchKernelGGL((k_matmul2<true, true, false>), dim3(B, L / 64), dim3(256), 0, stream,
                       X, enc_w[p], (const float*)X, X, pout, (float*)nullptr, L);
  };

  k_postab<<<64, 256, 0, stream>>>(postab);
  // ---- embeddings ----
  k_charembed<<<dim3(NN, B), 256, 0, stream>>>(Ccid, char_table, e2dw, e2db, e2pw, e2pb, E1, NN);
  k_embconv<<<dim3(NN, B), 64, 0, stream>>>(E1, Cwid, word_table, e1dw, e1db, e1pw, e1pb, E2, NN);
  k_highway<<<dim3(NN, B), 64, 0, stream>>>(E2, hlw, hlb, hgw, hgb, CX, NN);
  k_charembed<<<dim3(MQ, B), 256, 0, stream>>>(Qcid, char_table, e2dw, e2db, e2pw, e2pb, E1, MQ);
  k_embconv<<<dim3(MQ, B), 64, 0, stream>>>(E1, Qwid, word_table, e1dw, e1db, e1pw, e1pb, E2, MQ);
  k_highway<<<dim3(MQ, B), 64, 0, stream>>>(E2, hlw, hlb, hgw, hgb, QX, MQ);
  // ---- embedding encoders ----
  run_enc(CX, nullptr, 256, 4, 7, 0);
  run_enc(QX, nullptr, 64, 4, 7, 1);
  // ---- context-query attention ----
  k_cqS<<<dim3(B, 4), 256, 0, stream>>>(CX, QX, cq_w, Sb, rmax, rsum);
  k_cqcol<<<B, 64, 0, stream>>>(Sb, cmax, csum);
  k_cqA<<<dim3(B, 4), 256, 0, stream>>>(CX, QX, Sb, rmax, rsum, Xcat);
  k_cqCS2<<<B, 256, 0, stream>>>(CX, Sb, cmax, csum, CS2);
  k_cqBm<<<dim3(B, 4), 256, 0, stream>>>(CX, CS2, Sb, rmax, rsum, Xcat);
  // ---- resize -> M0 ----
  k_resize<<<dim3(B, 4), 256, 0, stream>>>(Xcat, rs_dw, rs_pw, M0);
  // ---- model encoders ----
  for (int r = 0; r < 7; ++r) run_enc(M0, nullptr, 256, 2, 5, 2);
  run_enc(M1, M0, 256, 2, 5, 3);
  for (int r = 1; r < 7; ++r) run_enc(M1, nullptr, 256, 2, 5, 3);
  run_enc(M2, M1, 256, 2, 5, 4);
  for (int r = 1; r < 7; ++r) run_enc(M2, nullptr, 256, 2, 5, 4);
  // ---- pointers ----
  k_pointer2<<<dim3(B, 2), 256, 0, stream>>>(M0, M1, M2, p_w0, p_w1, out);
}

// Round 13
// 4370.134 us; speedup vs baseline: 1.0605x; 1.0396x over previous
//
#include <hip/hip_runtime.h>
#include <math.h>

constexpr int B = 24, HH = 8;
constexpr int NN = 256, MQ = 64;
constexpr int EC = 364;

#define PI_2 1.5707963267948966f

// stats partials layout: parts[row][4][2], row = b*64+d
__device__ __forceinline__ void combine_stats(const float* __restrict__ parts,
                                              int row, int NT, float Lf,
                                              float& mu, float& inv) {
  float s = 0.f, q = 0.f;
  for (int t = 0; t < NT; ++t) {
    s += parts[((size_t)row * 4 + t) * 2];
    q += parts[((size_t)row * 4 + t) * 2 + 1];
  }
  mu = s / Lf;
  float var = (q - s * mu) / (Lf - 1.f);
  if (var < 0.f) var = 0.f;
  inv = 1.f / (sqrtf(var) + 1e-6f);
}

// ---------------- positional encoding table: tab[d*256+l] ----------------
__global__ void k_postab(float* __restrict__ tab) {
  int d = blockIdx.x, l = threadIdx.x;
  float fr = ((d & 1) == 0) ? powf(10000.f, -(float)d / 64.f)
                            : -powf(10000.f, -(float)(d - 1) / 64.f);
  float ph = (d & 1) ? PI_2 : 0.f;
  tab[d * 256 + l] = sinf(sinf((float)l * fr + ph));
}

// ---- one-time transpose of charembed pointwise weight: pwT[ce*64+o] ------
__global__ void k_pwT(const float* __restrict__ pw, float* __restrict__ pwT) {
  int i = blockIdx.x * 256 + threadIdx.x;
  if (i < 200 * 64) {
    int ce = i >> 6, o = i & 63;
    pwT[i] = pw[o * 200 + ce];
  }
}

// ---- X = (COPY? src : X) + tab ; emit per-tile row stats -----------------
template<bool COPY>
__global__ void k_posadd_stats(float* __restrict__ X, const float* __restrict__ src,
                               const float* __restrict__ tab, float* __restrict__ parts,
                               int L) {
  int row = blockIdx.x * 4 + (threadIdx.x >> 6);
  int lane = threadIdx.x & 63;
  int d = row & 63;
  float* xr = X + (size_t)row * L;
  const float* sr = COPY ? (src + (size_t)row * L) : xr;
  int NT = L >> 6;
  for (int t = 0; t < NT; ++t) {
    int l = t * 64 + lane;
    float v = sr[l] + tab[d * 256 + l];
    xr[l] = v;
    float s = v, q = v * v;
#pragma unroll
    for (int o = 32; o > 0; o >>= 1) { s += __shfl_xor(s, o); q += __shfl_xor(q, o); }
    if (lane == 0) {
      parts[((size_t)row * 4 + t) * 2] = s;
      parts[((size_t)row * 4 + t) * 2 + 1] = q;
    }
  }
}

// ---- fused: normalize -> dwconv(K) -> pw matmul -> relu -> +res -> X -----
template<int K>
__global__ __launch_bounds__(256) void k_fconv(
    float* __restrict__ X, const float* __restrict__ dw, const float* __restrict__ pw,
    const float* __restrict__ partsIn, float* __restrict__ partsOut, int L) {
  constexpr int H = K / 2, SW = 64 + 2 * H;
  __shared__ float smu[64], sinv[64];
  __shared__ float sN[64 * SW];
  __shared__ float sD[64 * 65];
  __shared__ float sWt[4096];
  int b = blockIdx.x, lt = blockIdx.y * 64;
  int tid = threadIdx.x;
  int NT = L >> 6;
  if (tid < 64) combine_stats(partsIn, b * 64 + tid, NT, (float)L, smu[tid], sinv[tid]);
  for (int i = tid; i < 4096; i += 256) sWt[i] = pw[i];
  __syncthreads();
  float* Xb = X + (size_t)b * 64 * L;
  for (int i = tid; i < 64 * SW; i += 256) {
    int c = i / SW, jj = i % SW;
    int gl = lt + jj - H;
    sN[i] = (gl >= 0 && gl < L) ? (Xb[(size_t)c * L + gl] - smu[c]) * sinv[c] : 0.f;
  }
  __syncthreads();
  for (int i = tid; i < 4096; i += 256) {
    int c = i >> 6, l = i & 63;
    float acc = 0.f;
#pragma unroll
    for (int k = 0; k < K; ++k) acc += sN[c * SW + l + k] * dw[c * K + k];
    sD[c * 65 + l] = acc;
  }
  __syncthreads();
  int l = tid & 63, og = tid >> 6;
  float acc[16];
#pragma unroll
  for (int j = 0; j < 16; ++j) acc[j] = 0.f;
  for (int c = 0; c < 64; ++c) {
    float av = sD[c * 65 + l];
#pragma unroll
    for (int j = 0; j < 16; ++j) acc[j] += sWt[(og * 16 + j) * 64 + c] * av;
  }
  __syncthreads();
#pragma unroll
  for (int j = 0; j < 16; ++j) {
    int o = og * 16 + j;
    float v = Xb[(size_t)o * L + lt + l] + fmaxf(acc[j], 0.f);
    Xb[(size_t)o * L + lt + l] = v;
    sD[o * 65 + l] = v;
  }
  __syncthreads();
  if (tid < 64) {
    int o = tid;
    float s = 0.f, q = 0.f;
    for (int l2 = 0; l2 < 64; ++l2) { float v = sD[o * 65 + l2]; s += v; q += v * v; }
    partsOut[((size_t)(b * 64 + o) * 4 + blockIdx.y) * 2] = s;
    partsOut[((size_t)(b * 64 + o) * 4 + blockIdx.y) * 2 + 1] = q;
  }
}

// ---- generic 64x64 matmul: out = res + act(W . (norm?)A) ; opt stats -----
template<bool NORM, bool RELU, bool STATS>
__global__ __launch_bounds__(256) void k_matmul2(
    const float* __restrict__ A, const float* __restrict__ W,
    const float* __restrict__ res, float* __restrict__ out,
    const float* __restrict__ partsIn, float* __restrict__ partsOut, int L) {
  __shared__ float sA[64 * 65];
  __shared__ float sW[4096];
  __shared__ float smu[64], sinv[64];
  int b = blockIdx.x, lt = blockIdx.y * 64;
  int tid = threadIdx.x;
  int NT = L >> 6;
  if (NORM && tid < 64) combine_stats(partsIn, b * 64 + tid, NT, (float)L, smu[tid], sinv[tid]);
  const float* Wb = W + (size_t)b * 4096;
  for (int i = tid; i < 4096; i += 256) sW[i] = Wb[i];
  if (NORM) __syncthreads();
  const float* Ab = A + (size_t)b * 64 * L;
  for (int i = tid; i < 4096; i += 256) {
    int c = i >> 6, ll = i & 63;
    float v = Ab[(size_t)c * L + lt + ll];
    if (NORM) v = (v - smu[c]) * sinv[c];
    sA[c * 65 + ll] = v;
  }
  __syncthreads();
  int l = tid & 63, og = tid >> 6;
  float acc[16];
#pragma unroll
  for (int j = 0; j < 16; ++j) acc[j] = 0.f;
  for (int c = 0; c < 64; ++c) {
    float av = sA[c * 65 + l];
#pragma unroll
    for (int j = 0; j < 16; ++j) acc[j] += sW[(og * 16 + j) * 64 + c] * av;
  }
  if (STATS) __syncthreads();
#pragma unroll
  for (int j = 0; j < 16; ++j) {
    int o = og * 16 + j;
    float v = acc[j];
    if (RELU) v = fmaxf(v, 0.f);
    size_t idx = ((size_t)b * 64 + o) * L + lt + l;
    v += res[idx];
    out[idx] = v;
    if (STATS) sA[o * 65 + l] = v;
  }
  if (STATS) {
    __syncthreads();
    if (tid < 64) {
      int o = tid;
      float s = 0.f, q = 0.f;
      for (int l2 = 0; l2 < 64; ++l2) { float v = sA[o * 65 + l2]; s += v; q += v * v; }
      partsOut[((size_t)(b * 64 + o) * 4 + blockIdx.y) * 2] = s;
      partsOut[((size_t)(b * 64 + o) * 4 + blockIdx.y) * 2 + 1] = q;
    }
  }
}

// ---- fused resize: M0[b,o,l] = sum_c pw[o,c] * dw5(Xcat)[b,c,l] ----------
__global__ __launch_bounds__(256) void k_resize(
    const float* __restrict__ Xcat, const float* __restrict__ dw,
    const float* __restrict__ pw, float* __restrict__ out) {
  __shared__ float sA[64 * 64];
  int b = blockIdx.x, lt = blockIdx.y * 64;
  int l = threadIdx.x & 63, og = threadIdx.x >> 6;
  float acc[16];
#pragma unroll
  for (int j = 0; j < 16; ++j) acc[j] = 0.f;
  for (int c0 = 0; c0 < 256; c0 += 64) {
    __syncthreads();
    for (int i = threadIdx.x; i < 4096; i += 256) {
      int c = (i >> 6) + c0, ll = (i & 63) + lt;
      const float* xr = Xcat + ((size_t)b * 256 + c) * 256;
      float a = 0.f;
#pragma unroll
      for (int k = 0; k < 5; ++k) {
        int p = ll + k - 2;
        if (p >= 0 && p < 256) a += xr[p] * dw[c * 5 + k];
      }
      sA[i] = a;
    }
    __syncthreads();
    for (int c = 0; c < 64; ++c) {
      float av = sA[c * 64 + l];
#pragma unroll
      for (int j = 0; j < 16; ++j)
        acc[j] += pw[(size_t)(og * 16 + j) * 256 + c0 + c] * av;
    }
  }
#pragma unroll
  for (int j = 0; j < 16; ++j)
    out[((size_t)b * 64 + og * 16 + j) * 256 + lt + l] = acc[j];
}

// ---- self-attention with inline norm, online softmax ---------------------
__global__ __launch_bounds__(256) void k_att(
    const float* __restrict__ X, const float* __restrict__ partsIn,
    const float* __restrict__ wq, const float* __restrict__ wk,
    const float* __restrict__ wv, float* __restrict__ hc, int L) {
  int h = blockIdx.x, b = blockIdx.y;
  __shared__ float smu[64], sinv[64];
  __shared__ float sX[64 * 65];
  __shared__ float sQ[8 * 256], sK8[8 * 256], sV[8 * 256];
  __shared__ float swq[512], swk[512], swv[512];
  int tid = threadIdx.x;
  int NT = L >> 6;
  if (tid < 64) combine_stats(partsIn, b * 64 + tid, NT, (float)L, smu[tid], sinv[tid]);
  size_t woff = (size_t)(h * B + b) * 512;
  for (int i = tid; i < 512; i += 256) {
    swq[i] = wq[woff + i]; swk[i] = wk[woff + i]; swv[i] = wv[woff + i];
  }
  __syncthreads();
  const float* Xb = X + (size_t)b * 64 * L;
  for (int lt = 0; lt < L; lt += 64) {
    for (int i = tid; i < 4096; i += 256) {
      int d = i >> 6, l = i & 63;
      sX[d * 65 + l] = (Xb[(size_t)d * L + lt + l] - smu[d]) * sinv[d];
    }
    __syncthreads();
    for (int i = tid; i < 512; i += 256) {
      int k = i >> 6, l = i & 63;
      float aq = 0.f, ak = 0.f, av = 0.f;
      for (int d = 0; d < 64; ++d) {
        float x = sX[d * 65 + l];
        aq += swq[k * 64 + d] * x;
        ak += swk[k * 64 + d] * x;
        av += swv[k * 64 + d] * x;
      }
      sQ[k * L + lt + l] = aq; sK8[k * L + lt + l] = ak; sV[k * L + lt + l] = av;
    }
    __syncthreads();
  }
  const float scale = 0.35355339059327373f;  // 1/sqrt(8)
  for (int m = tid; m < L; m += 256) {
    float kc[8];
#pragma unroll
    for (int k = 0; k < 8; ++k) kc[k] = sK8[k * L + m];
    float mx = -1e30f, sum = 0.f, acc[8];
#pragma unroll
    for (int v = 0; v < 8; ++v) acc[v] = 0.f;
    for (int l = 0; l < L; ++l) {
      float s = 0.f;
#pragma unroll
      for (int k = 0; k < 8; ++k) s += sQ[k * L + l] * kc[k];
      s *= scale;
      if (s <= mx) {
        float p = __expf(s - mx);
        sum += p;
#pragma unroll
        for (int v = 0; v < 8; ++v) acc[v] += p * sV[v * L + l];
      } else {
        float corr = __expf(mx - s);
        sum = sum * corr + 1.f;
#pragma unroll
        for (int v = 0; v < 8; ++v) acc[v] = acc[v] * corr + sV[v * L + l];
        mx = s;
      }
    }
    float is = 1.f / sum;
    for (int v = 0; v < 8; ++v)
      hc[((size_t)b * 64 + h * 8 + v) * L + m] = acc[v] * is;
  }
}

// ---- fused char embed: coalesced gather + TRANSPOSED pw (only change) ----
__global__ __launch_bounds__(256) void k_charembed(
    const int* __restrict__ cid, const float* __restrict__ ctab,
    const float* __restrict__ dw, const float* __restrict__ db,
    const float* __restrict__ pwT, const float* __restrict__ pb,
    float* __restrict__ out, int Ln) {
  int n = blockIdx.x, b = blockIdx.y;
  __shared__ float dwo[16 * 200];   // [cn][ce]
  __shared__ int sid[5][16];
  __shared__ float red[256];
  int tid = threadIdx.x;
  if (tid < 80) {
    int kn = tid / 16, cn = tid % 16;
    int nn = n + kn - 2;
    sid[kn][cn] = (nn >= 0 && nn < Ln) ? cid[((size_t)b * Ln + nn) * 16 + cn] : -1;
  }
  __syncthreads();
  for (int i = tid; i < 16 * 200; i += 256) {
    int cn = i / 200, ce = i % 200;
    float acc = db[ce];
    const float* wcc = dw + ce * 25;
#pragma unroll
    for (int kn = 0; kn < 5; ++kn) {
#pragma unroll
      for (int kc = 0; kc < 5; ++kc) {
        int cc = cn + kc - 2;
        if (cc < 0 || cc >= 16) continue;
        int id = sid[kn][cc];
        if (id >= 0) acc += ctab[(size_t)id * 200 + ce] * wcc[kn * 5 + kc];
      }
    }
    dwo[cn * 200 + ce] = acc;
  }
  __syncthreads();
  int o = tid & 63, q = tid >> 6;
  float mx = -1e30f;
  for (int cn = q; cn < 16; cn += 4) {
    float acc = pb[o];
    const float* dr = dwo + cn * 200;
    for (int ce = 0; ce < 200; ++ce) acc += pwT[ce * 64 + o] * dr[ce];
    mx = fmaxf(mx, acc);
  }
  red[tid] = mx;
  __syncthreads();
  if (q == 0) {
    mx = fmaxf(fmaxf(red[o], red[64 + o]), fmaxf(red[128 + o], red[192 + o]));
    out[((size_t)b * 64 + o) * Ln + n] = fmaxf(mx, 0.f);
  }
}

// ---- fused emb conv ------------------------------------------------------
__global__ void k_embconv(const float* __restrict__ chx, const int* __restrict__ wid,
                          const float* __restrict__ wtab, const float* __restrict__ dw,
                          const float* __restrict__ db, const float* __restrict__ pw,
                          const float* __restrict__ pb, float* __restrict__ out, int Ln) {
  int n = blockIdx.x, b = blockIdx.y;
  __shared__ float dwc[EC];
  __shared__ int sw[5];
  int tid = threadIdx.x;
  if (tid < 5) {
    int nn = n + tid - 2;
    sw[tid] = (nn >= 0 && nn < Ln) ? wid[(size_t)b * Ln + nn] : -1;
  }
  __syncthreads();
  for (int ch = tid; ch < EC; ch += 64) {
    float acc = db[ch];
#pragma unroll
    for (int k = 0; k < 5; ++k) {
      int nn = n + k - 2;
      float v = 0.f;
      if (nn >= 0 && nn < Ln) {
        if (ch < 64) v = chx[((size_t)b * 64 + ch) * Ln + nn];
        else v = wtab[(size_t)sw[k] * 300 + (ch - 64)];
      }
      acc += v * dw[ch * 5 + k];
    }
    dwc[ch] = acc;
  }
  __syncthreads();
  int o = tid;
  float acc = pb[o];
  const float* pwr = pw + o * EC;
  for (int c = 0; c < EC; ++c) acc += pwr[c] * dwc[c];
  out[((size_t)b * 64 + o) * Ln + n] = acc;
}

// ---------------- highway -------------------------------------------------
__global__ void k_highway(const float* __restrict__ inx, const float* __restrict__ lw,
                          const float* __restrict__ lb, const float* __restrict__ gw,
                          const float* __restrict__ gb, float* __restrict__ out, int Ln) {
  int n = blockIdx.x, b = blockIdx.y;
  __shared__ float x[64], xn[64];
  int o = threadIdx.x;
  x[o] = inx[((size_t)b * 64 + o) * Ln + n];
  __syncthreads();
  for (int layer = 0; layer < 2; ++layer) {
    const float* lwr = lw + (layer * 64 + o) * 64;
    const float* gwr = gw + (layer * 64 + o) * 64;
    float gl = gb[layer * 64 + o], nl = lb[layer * 64 + o];
    for (int d = 0; d < 64; ++d) { gl += gwr[d] * x[d]; nl += lwr[d] * x[d]; }
    float g = 1.f / (1.f + __expf(-gl));
    float r = fmaxf(nl, 0.f);
    xn[o] = g * r + (1.f - g) * x[o];
    __syncthreads();
    x[o] = xn[o];
    __syncthreads();
  }
  out[((size_t)b * 64 + o) * Ln + n] = x[o];
}

// ---------------- context-query attention ---------------------------------
__global__ __launch_bounds__(256) void k_cqS(const float* __restrict__ C,
                                             const float* __restrict__ Q,
                                             const float* __restrict__ w,
                                             float* __restrict__ S,
                                             float* __restrict__ rmax,
                                             float* __restrict__ rsum) {
  int b = blockIdx.x, nt = blockIdx.y * 64;
  __shared__ float sQ[4096], sC[4096], ct[64], qt[64], swb[192];
  const float* Cb = C + (size_t)b * 64 * 256;
  const float* Qb = Q + (size_t)b * 4096;
  const float* wb = w + (size_t)b * 192;
  if (threadIdx.x < 192) swb[threadIdx.x] = wb[threadIdx.x];
  for (int i = threadIdx.x; i < 4096; i += 256) {
    int d = i >> 6, m = i & 63;
    sQ[i] = Qb[d * 64 + m];
    sC[i] = Cb[d * 256 + nt + m];
  }
  __syncthreads();
  if (threadIdx.x < 64) {
    int j = threadIdx.x;
    float a = 0.f, c2 = 0.f;
    for (int d = 0; d < 64; ++d) {
      a += swb[64 + d] * sC[d * 64 + j];
      c2 += swb[d] * sQ[d * 64 + j];
    }
    ct[j] = a; qt[j] = c2;
  }
  __syncthreads();
  int m = threadIdx.x & 63, wv = threadIdx.x >> 6;
  for (int it = 0; it < 16; ++it) {
    int nl = wv + it * 4;
    float acc = ct[nl] + qt[m];
    for (int d = 0; d < 64; ++d)
      acc += sC[d * 64 + nl] * swb[128 + d] * sQ[d * 64 + m];
    S[((size_t)b * 256 + nt + nl) * 64 + m] = acc;
    float mx = acc;
#pragma unroll
    for (int o = 32; o > 0; o >>= 1) mx = fmaxf(mx, __shfl_xor(mx, o));
    float p = __expf(acc - mx);
#pragma unroll
    for (int o = 32; o > 0; o >>= 1) p += __shfl_xor(p, o);
    if (m == 0) { rmax[b * 256 + nt + nl] = mx; rsum[b * 256 + nt + nl] = p; }
  }
}

__global__ void k_cqcol(const float* __restrict__ S, float* __restrict__ cmax,
                        float* __restrict__ csum) {
  int b = blockIdx.x, m = threadIdx.x;
  const float* Sb = S + (size_t)b * 256 * 64;
  float mx = -1e30f;
  for (int n = 0; n < 256; ++n) mx = fmaxf(mx, Sb[n * 64 + m]);
  float s = 0.f;
  for (int n = 0; n < 256; ++n) s += __expf(Sb[n * 64 + m] - mx);
  cmax[b * 64 + m] = mx; csum[b * 64 + m] = s;
}

__global__ __launch_bounds__(256) void k_cqA(
    const float* __restrict__ C, const float* __restrict__ Q,
    const float* __restrict__ S, const float* __restrict__ rmax,
    const float* __restrict__ rsum, float* __restrict__ Xcat) {
  int b = blockIdx.x, nt = blockIdx.y * 64;
  __shared__ float sQ[4096];
  __shared__ float sP[64 * 65];
  const float* Qb = Q + (size_t)b * 4096;
  for (int i = threadIdx.x; i < 4096; i += 256) sQ[i] = Qb[i];
  for (int i = threadIdx.x; i < 4096; i += 256) {
    int nl = i >> 6, m = i & 63;
    int n = nt + nl;
    sP[nl * 65 + m] = __expf(S[((size_t)b * 256 + n) * 64 + m] - rmax[b * 256 + n]) / rsum[b * 256 + n];
  }
  __syncthreads();
  int nl = threadIdx.x & 63, dg = threadIdx.x >> 6;
  int n = nt + nl;
  for (int j = 0; j < 16; ++j) {
    int d = dg * 16 + j;
    float acc = 0.f;
    for (int m = 0; m < 64; ++m) acc += sQ[d * 64 + m] * sP[nl * 65 + m];
    float cv = C[((size_t)b * 64 + d) * 256 + n];
    Xcat[((size_t)b * 256 + d) * 256 + n] = cv;
    Xcat[((size_t)b * 256 + 64 + d) * 256 + n] = acc;
    Xcat[((size_t)b * 256 + 128 + d) * 256 + n] = cv * acc;
  }
}

// CS2[d,m] = sum_n C[d,n] * S2[n,m]
__global__ __launch_bounds__(256) void k_cqCS2(
    const float* __restrict__ C, const float* __restrict__ S,
    const float* __restrict__ cmax, const float* __restrict__ csum,
    float* __restrict__ CS2) {
  int b = blockIdx.x;
  __shared__ float sP[4096], sC[4096];
  int m = threadIdx.x & 63, dg = threadIdx.x >> 6;
  float acc[16];
#pragma unroll
  for (int j = 0; j < 16; ++j) acc[j] = 0.f;
  for (int nt = 0; nt < 4; ++nt) {
    __syncthreads();
    for (int i = threadIdx.x; i < 4096; i += 256) {
      int nl = i >> 6, mm = i & 63;
      int n = nt * 64 + nl;
      sP[i] = __expf(S[((size_t)b * 256 + n) * 64 + mm] - cmax[b * 64 + mm]) / csum[b * 64 + mm];
      int d = i >> 6, nn = i & 63;
      sC[i] = C[((size_t)b * 64 + d) * 256 + nt * 64 + nn];
    }
    __syncthreads();
    for (int nl = 0; nl < 64; ++nl) {
      float p = sP[nl * 64 + m];
#pragma unroll
      for (int j = 0; j < 16; ++j) acc[j] += sC[(dg * 16 + j) * 64 + nl] * p;
    }
  }
  for (int j = 0; j < 16; ++j)
    CS2[((size_t)b * 64 + dg * 16 + j) * 64 + m] = acc[j];
}

// Bm[d,k] = sum_m CS2[d,m] * S1[k,m]
__global__ __launch_bounds__(256) void k_cqBm(
    const float* __restrict__ C, const float* __restrict__ CS2,
    const float* __restrict__ S, const float* __restrict__ rmax,
    const float* __restrict__ rsum, float* __restrict__ Xcat) {
  int b = blockIdx.x, kt = blockIdx.y * 64;
  __shared__ float sW[4096];
  __shared__ float sP[64 * 65];
  for (int i = threadIdx.x; i < 4096; i += 256) sW[i] = CS2[(size_t)b * 4096 + i];
  for (int i = threadIdx.x; i < 4096; i += 256) {
    int kl = i >> 6, m = i & 63;
    int k = kt + kl;
    sP[kl * 65 + m] = __expf(S[((size_t)b * 256 + k) * 64 + m] - rmax[b * 256 + k]) / rsum[b * 256 + k];
  }
  __syncthreads();
  int kl = threadIdx.x & 63, dg = threadIdx.x >> 6;
  int k = kt + kl;
  for (int j = 0; j < 16; ++j) {
    int d = dg * 16 + j;
    float acc = 0.f;
    for (int m = 0; m < 64; ++m) acc += sW[d * 64 + m] * sP[kl * 65 + m];
    float cv = C[((size_t)b * 64 + d) * 256 + k];
    Xcat[((size_t)b * 256 + 192 + d) * 256 + k] = cv * acc;
  }
}

// ---- both pointers in one launch: grid (B, 2) ----------------------------
__global__ void k_pointer2(const float* __restrict__ M0, const float* __restrict__ M1,
                           const float* __restrict__ M2, const float* __restrict__ w0,
                           const float* __restrict__ w1, float* __restrict__ out) {
  int b = blockIdx.x, sel = blockIdx.y, n = threadIdx.x;
  const float* wb = (sel ? w1 : w0) + b * 128;
  const float* Mb = sel ? M2 : M1;
  float y = 0.f;
  for (int d = 0; d < 64; ++d) {
    y += wb[d] * M0[((size_t)b * 64 + d) * 256 + n];
    y += wb[64 + d] * Mb[((size_t)b * 64 + d) * 256 + n];
  }
  __shared__ float wred[4], wsum[4];
  int lane = n & 63, wid = n >> 6;
  float mx = y;
#pragma unroll
  for (int o = 32; o > 0; o >>= 1) mx = fmaxf(mx, __shfl_xor(mx, o));
  if (lane == 0) wred[wid] = mx;
  __syncthreads();
  mx = fmaxf(fmaxf(wred[0], wred[1]), fmaxf(wred[2], wred[3]));
  float e = __expf(y - mx);
  float s = e;
#pragma unroll
  for (int o = 32; o > 0; o >>= 1) s += __shfl_xor(s, o);
  if (lane == 0) wsum[wid] = s;
  __syncthreads();
  s = wsum[0] + wsum[1] + wsum[2] + wsum[3];
  out[sel * 6144 + b * 256 + n] = e / s;
}

// ===========================================================================
extern "C" void kernel_launch(void* const* d_in, const int* in_sizes, int n_in,
                              void* d_out, int out_size, void* d_ws, size_t ws_size,
                              hipStream_t stream) {
  const float* word_table = (const float*)d_in[0];
  const float* char_table = (const float*)d_in[1];
  const float* e2dw = (const float*)d_in[2];
  const float* e2db = (const float*)d_in[3];
  const float* e2pw = (const float*)d_in[4];
  const float* e2pb = (const float*)d_in[5];
  const float* e1dw = (const float*)d_in[6];
  const float* e1db = (const float*)d_in[7];
  const float* e1pw = (const float*)d_in[8];
  const float* e1pb = (const float*)d_in[9];
  const float* hlw = (const float*)d_in[10];
  const float* hlb = (const float*)d_in[11];
  const float* hgw = (const float*)d_in[12];
  const float* hgb = (const float*)d_in[13];
  const float *enc_dw[5], *enc_pw[5], *enc_wq[5], *enc_wk[5], *enc_wv[5], *enc_wo[5], *enc_w[5];
  for (int p = 0; p < 5; ++p) {
    enc_dw[p] = (const float*)d_in[14 + 7 * p + 0];
    enc_pw[p] = (const float*)d_in[14 + 7 * p + 1];
    enc_wq[p] = (const float*)d_in[14 + 7 * p + 2];
    enc_wk[p] = (const float*)d_in[14 + 7 * p + 3];
    enc_wv[p] = (const float*)d_in[14 + 7 * p + 4];
    enc_wo[p] = (const float*)d_in[14 + 7 * p + 5];
    enc_w[p]  = (const float*)d_in[14 + 7 * p + 6];
  }
  const float* cq_w  = (const float*)d_in[49];
  const float* rs_dw = (const float*)d_in[50];
  const float* rs_pw = (const float*)d_in[51];
  const float* p_w0  = (const float*)d_in[52];
  const float* p_w1  = (const float*)d_in[53];
  const int* Cwid = (const int*)d_in[54];
  const int* Ccid = (const int*)d_in[55];
  const int* Qwid = (const int*)d_in[56];
  const int* Qcid = (const int*)d_in[57];
  float* out = (float*)d_out;

  // ---- workspace (floats), ~12.1 MB --------------------------------------
  float* ws = (float*)d_ws;
  float* postab = ws;                  // 16384
  float* U    = ws + 16384;            // 393216  (att head out)
  float* Xcat = ws + 409600;           // 1572864 ; M2 aliases; emb scratch
  float* CX   = ws + 1982464;          // 393216  ; M0 aliases
  float* Sb   = ws + 2375680;          // 393216  ; M1 aliases
  float* QX   = ws + 2768896;          // 98304
  float* CS2  = ws + 2867200;          // 98304
  float* rmax = ws + 2965504;          // 6144
  float* rsum = ws + 2971648;          // 6144
  float* cmax = ws + 2977792;          // 1536
  float* csum = ws + 2979328;          // 1536
  float* P0   = ws + 2980864;          // 12288
  float* P1   = ws + 2993152;          // 12288
  float* pwT  = ws + 3005440;          // 12800  -> ends 3018240
  float* M0 = CX; float* M1 = Sb; float* M2 = Xcat;
  float* E1 = Xcat; float* E2 = Xcat + 393216;
  (void)out_size; (void)in_sizes; (void)n_in; (void)ws_size;

  auto run_enc = [&](float* X, const float* src, int L, int cnum, int K, int p) {
    int NB = B * 64 / 4;
    if (src)
      hipLaunchKernelGGL((k_posadd_stats<true>), dim3(NB), dim3(256), 0, stream, X, src, postab, P0, L);
    else
      hipLaunchKernelGGL((k_posadd_stats<false>), dim3(NB), dim3(256), 0, stream, X, (const float*)nullptr, postab, P0, L);
    float* pin = P0; float* pout = P1;
    for (int i = 0; i < cnum; ++i) {
      if (K == 7)
        hipLaunchKernelGGL((k_fconv<7>), dim3(B, L / 64), dim3(256), 0, stream,
                           X, enc_dw[p] + i * 64 * 7, enc_pw[p] + (size_t)i * 4096, pin, pout, L);
      else
        hipLaunchKernelGGL((k_fconv<5>), dim3(B, L / 64), dim3(256), 0, stream,
                           X, enc_dw[p] + i * 64 * 5, enc_pw[p] + (size_t)i * 4096, pin, pout, L);
      float* t = pin; pin = pout; pout = t;
    }
    k_att<<<dim3(HH, B), 256, 0, stream>>>(X, pin, enc_wq[p], enc_wk[p], enc_wv[p], U, L);
    hipLaunchKernelGGL((k_matmul2<false, false, true>), dim3(B, L / 64), dim3(256), 0, stream,
                       U, enc_wo[p], (const float*)X, X, (const float*)nullptr, pout, L);
    hipLaunchKernelGGL((k_matmul2<true, true, false>), dim3(B, L / 64), dim3(256), 0, stream,
                       X, enc_w[p], (const float*)X, X, pout, (float*)nullptr, L);
  };

  k_postab<<<64, 256, 0, stream>>>(postab);
  k_pwT<<<50, 256, 0, stream>>>(e2pw, pwT);
  // ---- embeddings ----
  k_charembed<<<dim3(NN, B), 256, 0, stream>>>(Ccid, char_table, e2dw, e2db, pwT, e2pb, E1, NN);
  k_embconv<<<dim3(NN, B), 64, 0, stream>>>(E1, Cwid, word_table, e1dw, e1db, e1pw, e1pb, E2, NN);
  k_highway<<<dim3(NN, B), 64, 0, stream>>>(E2, hlw, hlb, hgw, hgb, CX, NN);
  k_charembed<<<dim3(MQ, B), 256, 0, stream>>>(Qcid, char_table, e2dw, e2db, pwT, e2pb, E1, MQ);
  k_embconv<<<dim3(MQ, B), 64, 0, stream>>>(E1, Qwid, word_table, e1dw, e1db, e1pw, e1pb, E2, MQ);
  k_highway<<<dim3(MQ, B), 64, 0, stream>>>(E2, hlw, hlb, hgw, hgb, QX, MQ);
  // ---- embedding encoders ----
  run_enc(CX, nullptr, 256, 4, 7, 0);
  run_enc(QX, nullptr, 64, 4, 7, 1);
  // ---- context-query attention ----
  k_cqS<<<dim3(B, 4), 256, 0, stream>>>(CX, QX, cq_w, Sb, rmax, rsum);
  k_cqcol<<<B, 64, 0, stream>>>(Sb, cmax, csum);
  k_cqA<<<dim3(B, 4), 256, 0, stream>>>(CX, QX, Sb, rmax, rsum, Xcat);
  k_cqCS2<<<B, 256, 0, stream>>>(CX, Sb, cmax, csum, CS2);
  k_cqBm<<<dim3(B, 4), 256, 0, stream>>>(CX, CS2, Sb, rmax, rsum, Xcat);
  // ---- resize -> M0 ----
  k_resize<<<dim3(B, 4), 256, 0, stream>>>(Xcat, rs_dw, rs_pw, M0);
  // ---- model encoders ----
  for (int r = 0; r < 7; ++r) run_enc(M0, nullptr, 256, 2, 5, 2);
  run_enc(M1, M0, 256, 2, 5, 3);
  for (int r = 1; r < 7; ++r) run_enc(M1, nullptr, 256, 2, 5, 3);
  run_enc(M2, M1, 256, 2, 5, 4);
  for (int r = 1; r < 7; ++r) run_enc(M2, nullptr, 256, 2, 5, 4);
  // ---- pointers ----
  k_pointer2<<<dim3(B, 2), 256, 0, stream>>>(M0, M1, M2, p_w0, p_w1, out);
}

// Round 14
// 3930.050 us; speedup vs baseline: 1.1793x; 1.1120x over previous
//
#include <hip/hip_runtime.h>
#include <math.h>

constexpr int B = 24, HH = 8;
constexpr int NN = 256, MQ = 64;
constexpr int EC = 364;

#define PI_2 1.5707963267948966f

// stats partials layout: parts[row][4][2], row = b*64+d
__device__ __forceinline__ void combine_stats(const float* __restrict__ parts,
                                              int row, int NT, float Lf,
                                              float& mu, float& inv) {
  float s = 0.f, q = 0.f;
  for (int t = 0; t < NT; ++t) {
    s += parts[((size_t)row * 4 + t) * 2];
    q += parts[((size_t)row * 4 + t) * 2 + 1];
  }
  mu = s / Lf;
  float var = (q - s * mu) / (Lf - 1.f);
  if (var < 0.f) var = 0.f;
  inv = 1.f / (sqrtf(var) + 1e-6f);
}

// ---------------- positional encoding table: tab[d*256+l] ----------------
__global__ void k_postab(float* __restrict__ tab) {
  int d = blockIdx.x, l = threadIdx.x;
  float fr = ((d & 1) == 0) ? powf(10000.f, -(float)d / 64.f)
                            : -powf(10000.f, -(float)(d - 1) / 64.f);
  float ph = (d & 1) ? PI_2 : 0.f;
  tab[d * 256 + l] = sinf(sinf((float)l * fr + ph));
}

// ---- weight transposes (one-time) ----------------------------------------
__global__ void k_pwT(const float* __restrict__ pw, float* __restrict__ pwT) {
  int i = blockIdx.x * 256 + threadIdx.x;
  if (i < 200 * 64) {
    int ce = i >> 6, o = i & 63;
    pwT[i] = pw[o * 200 + ce];
  }
}
__global__ void k_pwT2(const float* __restrict__ pw, float* __restrict__ pwT) {
  int i = blockIdx.x * 256 + threadIdx.x;
  if (i < EC * 64) {
    int c = i >> 6, o = i & 63;
    pwT[i] = pw[o * EC + c];
  }
}
__global__ void k_hwT(const float* __restrict__ w, float* __restrict__ wT) {
  int i = blockIdx.x * 256 + threadIdx.x;
  if (i < 8192) {
    int layer = i >> 12, rem = i & 4095;
    int d = rem >> 6, o = rem & 63;
    wT[i] = w[layer * 4096 + o * 64 + d];
  }
}

// ---- X = (COPY? src : X) + tab ; emit per-tile row stats -----------------
template<bool COPY>
__global__ void k_posadd_stats(float* __restrict__ X, const float* __restrict__ src,
                               const float* __restrict__ tab, float* __restrict__ parts,
                               int L) {
  int row = blockIdx.x * 4 + (threadIdx.x >> 6);
  int lane = threadIdx.x & 63;
  int d = row & 63;
  float* xr = X + (size_t)row * L;
  const float* sr = COPY ? (src + (size_t)row * L) : xr;
  int NT = L >> 6;
  for (int t = 0; t < NT; ++t) {
    int l = t * 64 + lane;
    float v = sr[l] + tab[d * 256 + l];
    xr[l] = v;
    float s = v, q = v * v;
#pragma unroll
    for (int o = 32; o > 0; o >>= 1) { s += __shfl_xor(s, o); q += __shfl_xor(q, o); }
    if (lane == 0) {
      parts[((size_t)row * 4 + t) * 2] = s;
      parts[((size_t)row * 4 + t) * 2 + 1] = q;
    }
  }
}

// ---- fused: normalize -> dwconv(K) -> pw matmul -> relu -> +res -> X -----
template<int K>
__global__ __launch_bounds__(256) void k_fconv(
    float* __restrict__ X, const float* __restrict__ dw, const float* __restrict__ pw,
    const float* __restrict__ partsIn, float* __restrict__ partsOut, int L) {
  constexpr int H = K / 2, SW = 64 + 2 * H;
  __shared__ float smu[64], sinv[64];
  __shared__ float sN[64 * SW];
  __shared__ float sD[64 * 65];
  __shared__ float sWt[4096];
  int b = blockIdx.x, lt = blockIdx.y * 64;
  int tid = threadIdx.x;
  int NT = L >> 6;
  if (tid < 64) combine_stats(partsIn, b * 64 + tid, NT, (float)L, smu[tid], sinv[tid]);
  for (int i = tid; i < 4096; i += 256) sWt[i] = pw[i];
  __syncthreads();
  float* Xb = X + (size_t)b * 64 * L;
  for (int i = tid; i < 64 * SW; i += 256) {
    int c = i / SW, jj = i % SW;
    int gl = lt + jj - H;
    sN[i] = (gl >= 0 && gl < L) ? (Xb[(size_t)c * L + gl] - smu[c]) * sinv[c] : 0.f;
  }
  __syncthreads();
  for (int i = tid; i < 4096; i += 256) {
    int c = i >> 6, l = i & 63;
    float acc = 0.f;
#pragma unroll
    for (int k = 0; k < K; ++k) acc += sN[c * SW + l + k] * dw[c * K + k];
    sD[c * 65 + l] = acc;
  }
  __syncthreads();
  int l = tid & 63, og = tid >> 6;
  float acc[16];
#pragma unroll
  for (int j = 0; j < 16; ++j) acc[j] = 0.f;
  for (int c = 0; c < 64; ++c) {
    float av = sD[c * 65 + l];
#pragma unroll
    for (int j = 0; j < 16; ++j) acc[j] += sWt[(og * 16 + j) * 64 + c] * av;
  }
  __syncthreads();
#pragma unroll
  for (int j = 0; j < 16; ++j) {
    int o = og * 16 + j;
    float v = Xb[(size_t)o * L + lt + l] + fmaxf(acc[j], 0.f);
    Xb[(size_t)o * L + lt + l] = v;
    sD[o * 65 + l] = v;
  }
  __syncthreads();
  if (tid < 64) {
    int o = tid;
    float s = 0.f, q = 0.f;
    for (int l2 = 0; l2 < 64; ++l2) { float v = sD[o * 65 + l2]; s += v; q += v * v; }
    partsOut[((size_t)(b * 64 + o) * 4 + blockIdx.y) * 2] = s;
    partsOut[((size_t)(b * 64 + o) * 4 + blockIdx.y) * 2 + 1] = q;
  }
}

// ---- generic 64x64 matmul: out = res + act(W . (norm?)A) ; opt stats -----
template<bool NORM, bool RELU, bool STATS>
__global__ __launch_bounds__(256) void k_matmul2(
    const float* __restrict__ A, const float* __restrict__ W,
    const float* __restrict__ res, float* __restrict__ out,
    const float* __restrict__ partsIn, float* __restrict__ partsOut, int L) {
  __shared__ float sA[64 * 65];
  __shared__ float sW[4096];
  __shared__ float smu[64], sinv[64];
  int b = blockIdx.x, lt = blockIdx.y * 64;
  int tid = threadIdx.x;
  int NT = L >> 6;
  if (NORM && tid < 64) combine_stats(partsIn, b * 64 + tid, NT, (float)L, smu[tid], sinv[tid]);
  const float* Wb = W + (size_t)b * 4096;
  for (int i = tid; i < 4096; i += 256) sW[i] = Wb[i];
  if (NORM) __syncthreads();
  const float* Ab = A + (size_t)b * 64 * L;
  for (int i = tid; i < 4096; i += 256) {
    int c = i >> 6, ll = i & 63;
    float v = Ab[(size_t)c * L + lt + ll];
    if (NORM) v = (v - smu[c]) * sinv[c];
    sA[c * 65 + ll] = v;
  }
  __syncthreads();
  int l = tid & 63, og = tid >> 6;
  float acc[16];
#pragma unroll
  for (int j = 0; j < 16; ++j) acc[j] = 0.f;
  for (int c = 0; c < 64; ++c) {
    float av = sA[c * 65 + l];
#pragma unroll
    for (int j = 0; j < 16; ++j) acc[j] += sW[(og * 16 + j) * 64 + c] * av;
  }
  if (STATS) __syncthreads();
#pragma unroll
  for (int j = 0; j < 16; ++j) {
    int o = og * 16 + j;
    float v = acc[j];
    if (RELU) v = fmaxf(v, 0.f);
    size_t idx = ((size_t)b * 64 + o) * L + lt + l;
    v += res[idx];
    out[idx] = v;
    if (STATS) sA[o * 65 + l] = v;
  }
  if (STATS) {
    __syncthreads();
    if (tid < 64) {
      int o = tid;
      float s = 0.f, q = 0.f;
      for (int l2 = 0; l2 < 64; ++l2) { float v = sA[o * 65 + l2]; s += v; q += v * v; }
      partsOut[((size_t)(b * 64 + o) * 4 + blockIdx.y) * 2] = s;
      partsOut[((size_t)(b * 64 + o) * 4 + blockIdx.y) * 2 + 1] = q;
    }
  }
}

// ---- fused resize: M0[b,o,l] = sum_c pw[o,c] * dw5(Xcat)[b,c,l] ----------
__global__ __launch_bounds__(256) void k_resize(
    const float* __restrict__ Xcat, const float* __restrict__ dw,
    const float* __restrict__ pw, float* __restrict__ out) {
  __shared__ float sA[64 * 64];
  int b = blockIdx.x, lt = blockIdx.y * 64;
  int l = threadIdx.x & 63, og = threadIdx.x >> 6;
  float acc[16];
#pragma unroll
  for (int j = 0; j < 16; ++j) acc[j] = 0.f;
  for (int c0 = 0; c0 < 256; c0 += 64) {
    __syncthreads();
    for (int i = threadIdx.x; i < 4096; i += 256) {
      int c = (i >> 6) + c0, ll = (i & 63) + lt;
      const float* xr = Xcat + ((size_t)b * 256 + c) * 256;
      float a = 0.f;
#pragma unroll
      for (int k = 0; k < 5; ++k) {
        int p = ll + k - 2;
        if (p >= 0 && p < 256) a += xr[p] * dw[c * 5 + k];
      }
      sA[i] = a;
    }
    __syncthreads();
    for (int c = 0; c < 64; ++c) {
      float av = sA[c * 64 + l];
#pragma unroll
      for (int j = 0; j < 16; ++j)
        acc[j] += pw[(size_t)(og * 16 + j) * 256 + c0 + c] * av;
    }
  }
#pragma unroll
  for (int j = 0; j < 16; ++j)
    out[((size_t)b * 64 + og * 16 + j) * 256 + lt + l] = acc[j];
}

// ---- self-attention with inline norm, online softmax ---------------------
__global__ __launch_bounds__(256) void k_att(
    const float* __restrict__ X, const float* __restrict__ partsIn,
    const float* __restrict__ wq, const float* __restrict__ wk,
    const float* __restrict__ wv, float* __restrict__ hc, int L) {
  int h = blockIdx.x, b = blockIdx.y;
  __shared__ float smu[64], sinv[64];
  __shared__ float sX[64 * 65];
  __shared__ float sQ[8 * 256], sK8[8 * 256], sV[8 * 256];
  __shared__ float swq[512], swk[512], swv[512];
  int tid = threadIdx.x;
  int NT = L >> 6;
  if (tid < 64) combine_stats(partsIn, b * 64 + tid, NT, (float)L, smu[tid], sinv[tid]);
  size_t woff = (size_t)(h * B + b) * 512;
  for (int i = tid; i < 512; i += 256) {
    swq[i] = wq[woff + i]; swk[i] = wk[woff + i]; swv[i] = wv[woff + i];
  }
  __syncthreads();
  const float* Xb = X + (size_t)b * 64 * L;
  for (int lt = 0; lt < L; lt += 64) {
    for (int i = tid; i < 4096; i += 256) {
      int d = i >> 6, l = i & 63;
      sX[d * 65 + l] = (Xb[(size_t)d * L + lt + l] - smu[d]) * sinv[d];
    }
    __syncthreads();
    for (int i = tid; i < 512; i += 256) {
      int k = i >> 6, l = i & 63;
      float aq = 0.f, ak = 0.f, av = 0.f;
      for (int d = 0; d < 64; ++d) {
        float x = sX[d * 65 + l];
        aq += swq[k * 64 + d] * x;
        ak += swk[k * 64 + d] * x;
        av += swv[k * 64 + d] * x;
      }
      sQ[k * L + lt + l] = aq; sK8[k * L + lt + l] = ak; sV[k * L + lt + l] = av;
    }
    __syncthreads();
  }
  const float scale = 0.35355339059327373f;  // 1/sqrt(8)
  for (int m = tid; m < L; m += 256) {
    float kc[8];
#pragma unroll
    for (int k = 0; k < 8; ++k) kc[k] = sK8[k * L + m];
    float mx = -1e30f, sum = 0.f, acc[8];
#pragma unroll
    for (int v = 0; v < 8; ++v) acc[v] = 0.f;
    for (int l = 0; l < L; ++l) {
      float s = 0.f;
#pragma unroll
      for (int k = 0; k < 8; ++k) s += sQ[k * L + l] * kc[k];
      s *= scale;
      if (s <= mx) {
        float p = __expf(s - mx);
        sum += p;
#pragma unroll
        for (int v = 0; v < 8; ++v) acc[v] += p * sV[v * L + l];
      } else {
        float corr = __expf(mx - s);
        sum = sum * corr + 1.f;
#pragma unroll
        for (int v = 0; v < 8; ++v) acc[v] = acc[v] * corr + sV[v * L + l];
        mx = s;
      }
    }
    float is = 1.f / sum;
    for (int v = 0; v < 8; ++v)
      hc[((size_t)b * 64 + h * 8 + v) * L + m] = acc[v] * is;
  }
}

// ---- fused char embed: register-staged taps + LDS dw + chunked pwT -------
__global__ __launch_bounds__(256) void k_charembed(
    const int* __restrict__ cid, const float* __restrict__ ctab,
    const float* __restrict__ dw, const float* __restrict__ db,
    const float* __restrict__ pwT, const float* __restrict__ pb,
    float* __restrict__ out, int Ln) {
  int n = blockIdx.x, b = blockIdx.y;
  __shared__ float dwo[16 * 200];   // [cn][ce]
  __shared__ float sdw[5000];       // dw staged: [ce][25]
  __shared__ int sid[5][16];
  __shared__ float red[256];
  int tid = threadIdx.x;
  if (tid < 80) {
    int kn = tid / 16, cn = tid % 16;
    int nn = n + kn - 2;
    sid[kn][cn] = (nn >= 0 && nn < Ln) ? cid[((size_t)b * Ln + nn) * 16 + cn] : -1;
  }
  for (int i = tid; i < 5000; i += 256) sdw[i] = dw[i];
  __syncthreads();
  for (int i = tid; i < 16 * 200; i += 256) {
    int cn = i / 200, ce = i % 200;
    const float* wcc = sdw + ce * 25;
    float r[25];
#pragma unroll
    for (int kn = 0; kn < 5; ++kn) {
#pragma unroll
      for (int kc = 0; kc < 5; ++kc) {
        int cc = cn + kc - 2;
        int id = (cc >= 0 && cc < 16) ? sid[kn][cc] : -1;
        r[kn * 5 + kc] = (id >= 0) ? ctab[(size_t)id * 200 + ce] : 0.f;
      }
    }
    float acc = db[ce];
#pragma unroll
    for (int t = 0; t < 25; ++t) acc += r[t] * wcc[t];
    dwo[cn * 200 + ce] = acc;
  }
  __syncthreads();
  int o = tid & 63, q = tid >> 6;
  float mx = -1e30f;
  for (int cn = q; cn < 16; cn += 4) {
    float acc = pb[o];
    const float* dr = dwo + cn * 200;
    for (int c0 = 0; c0 < 200; c0 += 8) {
      float w8[8];
#pragma unroll
      for (int j = 0; j < 8; ++j) w8[j] = pwT[(c0 + j) * 64 + o];
#pragma unroll
      for (int j = 0; j < 8; ++j) acc += w8[j] * dr[c0 + j];
    }
    mx = fmaxf(mx, acc);
  }
  red[tid] = mx;
  __syncthreads();
  if (q == 0) {
    mx = fmaxf(fmaxf(red[o], red[64 + o]), fmaxf(red[128 + o], red[192 + o]));
    out[((size_t)b * 64 + o) * Ln + n] = fmaxf(mx, 0.f);
  }
}

// ---- fused emb conv: transposed pw + chunked register staging ------------
__global__ void k_embconv(const float* __restrict__ chx, const int* __restrict__ wid,
                          const float* __restrict__ wtab, const float* __restrict__ dw,
                          const float* __restrict__ db, const float* __restrict__ pwT,
                          const float* __restrict__ pb, float* __restrict__ out, int Ln) {
  int n = blockIdx.x, b = blockIdx.y;
  __shared__ float dwc[EC];
  __shared__ int sw[5];
  int tid = threadIdx.x;
  if (tid < 5) {
    int nn = n + tid - 2;
    sw[tid] = (nn >= 0 && nn < Ln) ? wid[(size_t)b * Ln + nn] : -1;
  }
  __syncthreads();
  for (int ch = tid; ch < EC; ch += 64) {
    float r[5];
#pragma unroll
    for (int k = 0; k < 5; ++k) {
      int nn = n + k - 2;
      float v = 0.f;
      if (nn >= 0 && nn < Ln) {
        if (ch < 64) v = chx[((size_t)b * 64 + ch) * Ln + nn];
        else v = wtab[(size_t)sw[k] * 300 + (ch - 64)];
      }
      r[k] = v;
    }
    float acc = db[ch];
#pragma unroll
    for (int k = 0; k < 5; ++k) acc += r[k] * dw[ch * 5 + k];
    dwc[ch] = acc;
  }
  __syncthreads();
  int o = tid;
  float acc = pb[o];
  for (int c0 = 0; c0 < EC; c0 += 4) {
    float w4[4];
#pragma unroll
    for (int j = 0; j < 4; ++j) w4[j] = pwT[(c0 + j) * 64 + o];
#pragma unroll
    for (int j = 0; j < 4; ++j) acc += w4[j] * dwc[c0 + j];
  }
  out[((size_t)b * 64 + o) * Ln + n] = acc;
}

// ---------------- highway: transposed weights + chunked staging -----------
__global__ void k_highway(const float* __restrict__ inx, const float* __restrict__ lwT,
                          const float* __restrict__ lb, const float* __restrict__ gwT,
                          const float* __restrict__ gb, float* __restrict__ out, int Ln) {
  int n = blockIdx.x, b = blockIdx.y;
  __shared__ float x[64], xn[64];
  int o = threadIdx.x;
  x[o] = inx[((size_t)b * 64 + o) * Ln + n];
  __syncthreads();
  for (int layer = 0; layer < 2; ++layer) {
    const float* lwr = lwT + layer * 4096;
    const float* gwr = gwT + layer * 4096;
    float gl = gb[layer * 64 + o], nl = lb[layer * 64 + o];
    for (int d0 = 0; d0 < 64; d0 += 8) {
      float g8[8], l8[8];
#pragma unroll
      for (int j = 0; j < 8; ++j) { g8[j] = gwr[(d0 + j) * 64 + o]; l8[j] = lwr[(d0 + j) * 64 + o]; }
#pragma unroll
      for (int j = 0; j < 8; ++j) { gl += g8[j] * x[d0 + j]; nl += l8[j] * x[d0 + j]; }
    }
    float g = 1.f / (1.f + __expf(-gl));
    float r = fmaxf(nl, 0.f);
    xn[o] = g * r + (1.f - g) * x[o];
    __syncthreads();
    x[o] = xn[o];
    __syncthreads();
  }
  out[((size_t)b * 64 + o) * Ln + n] = x[o];
}

// ---------------- context-query attention ---------------------------------
__global__ __launch_bounds__(256) void k_cqS(const float* __restrict__ C,
                                             const float* __restrict__ Q,
                                             const float* __restrict__ w,
                                             float* __restrict__ S,
                                             float* __restrict__ rmax,
                                             float* __restrict__ rsum) {
  int b = blockIdx.x, nt = blockIdx.y * 64;
  __shared__ float sQ[4096], sC[4096], ct[64], qt[64], swb[192];
  const float* Cb = C + (size_t)b * 64 * 256;
  const float* Qb = Q + (size_t)b * 4096;
  const float* wb = w + (size_t)b * 192;
  if (threadIdx.x < 192) swb[threadIdx.x] = wb[threadIdx.x];
  for (int i = threadIdx.x; i < 4096; i += 256) {
    int d = i >> 6, m = i & 63;
    sQ[i] = Qb[d * 64 + m];
    sC[i] = Cb[d * 256 + nt + m];
  }
  __syncthreads();
  if (threadIdx.x < 64) {
    int j = threadIdx.x;
    float a = 0.f, c2 = 0.f;
    for (int d = 0; d < 64; ++d) {
      a += swb[64 + d] * sC[d * 64 + j];
      c2 += swb[d] * sQ[d * 64 + j];
    }
    ct[j] = a; qt[j] = c2;
  }
  __syncthreads();
  int m = threadIdx.x & 63, wv = threadIdx.x >> 6;
  for (int it = 0; it < 16; ++it) {
    int nl = wv + it * 4;
    float acc = ct[nl] + qt[m];
    for (int d = 0; d < 64; ++d)
      acc += sC[d * 64 + nl] * swb[128 + d] * sQ[d * 64 + m];
    S[((size_t)b * 256 + nt + nl) * 64 + m] = acc;
    float mx = acc;
#pragma unroll
    for (int o = 32; o > 0; o >>= 1) mx = fmaxf(mx, __shfl_xor(mx, o));
    float p = __expf(acc - mx);
#pragma unroll
    for (int o = 32; o > 0; o >>= 1) p += __shfl_xor(p, o);
    if (m == 0) { rmax[b * 256 + nt + nl] = mx; rsum[b * 256 + nt + nl] = p; }
  }
}

__global__ void k_cqcol(const float* __restrict__ S, float* __restrict__ cmax,
                        float* __restrict__ csum) {
  int b = blockIdx.x, m = threadIdx.x;
  const float* Sb = S + (size_t)b * 256 * 64;
  float mx = -1e30f;
  for (int n = 0; n < 256; ++n) mx = fmaxf(mx, Sb[n * 64 + m]);
  float s = 0.f;
  for (int n = 0; n < 256; ++n) s += __expf(Sb[n * 64 + m] - mx);
  cmax[b * 64 + m] = mx; csum[b * 64 + m] = s;
}

__global__ __launch_bounds__(256) void k_cqA(
    const float* __restrict__ C, const float* __restrict__ Q,
    const float* __restrict__ S, const float* __restrict__ rmax,
    const float* __restrict__ rsum, float* __restrict__ Xcat) {
  int b = blockIdx.x, nt = blockIdx.y * 64;
  __shared__ float sQ[4096];
  __shared__ float sP[64 * 65];
  const float* Qb = Q + (size_t)b * 4096;
  for (int i = threadIdx.x; i < 4096; i += 256) sQ[i] = Qb[i];
  for (int i = threadIdx.x; i < 4096; i += 256) {
    int nl = i >> 6, m = i & 63;
    int n = nt + nl;
    sP[nl * 65 + m] = __expf(S[((size_t)b * 256 + n) * 64 + m] - rmax[b * 256 + n]) / rsum[b * 256 + n];
  }
  __syncthreads();
  int nl = threadIdx.x & 63, dg = threadIdx.x >> 6;
  int n = nt + nl;
  for (int j = 0; j < 16; ++j) {
    int d = dg * 16 + j;
    float acc = 0.f;
    for (int m = 0; m < 64; ++m) acc += sQ[d * 64 + m] * sP[nl * 65 + m];
    float cv = C[((size_t)b * 64 + d) * 256 + n];
    Xcat[((size_t)b * 256 + d) * 256 + n] = cv;
    Xcat[((size_t)b * 256 + 64 + d) * 256 + n] = acc;
    Xcat[((size_t)b * 256 + 128 + d) * 256 + n] = cv * acc;
  }
}

// CS2[d,m] = sum_n C[d,n] * S2[n,m]
__global__ __launch_bounds__(256) void k_cqCS2(
    const float* __restrict__ C, const float* __restrict__ S,
    const float* __restrict__ cmax, const float* __restrict__ csum,
    float* __restrict__ CS2) {
  int b = blockIdx.x;
  __shared__ float sP[4096], sC[4096];
  int m = threadIdx.x & 63, dg = threadIdx.x >> 6;
  float acc[16];
#pragma unroll
  for (int j = 0; j < 16; ++j) acc[j] = 0.f;
  for (int nt = 0; nt < 4; ++nt) {
    __syncthreads();
    for (int i = threadIdx.x; i < 4096; i += 256) {
      int nl = i >> 6, mm = i & 63;
      int n = nt * 64 + nl;
      sP[i] = __expf(S[((size_t)b * 256 + n) * 64 + mm] - cmax[b * 64 + mm]) / csum[b * 64 + mm];
      int d = i >> 6, nn = i & 63;
      sC[i] = C[((size_t)b * 64 + d) * 256 + nt * 64 + nn];
    }
    __syncthreads();
    for (int nl = 0; nl < 64; ++nl) {
      float p = sP[nl * 64 + m];
#pragma unroll
      for (int j = 0; j < 16; ++j) acc[j] += sC[(dg * 16 + j) * 64 + nl] * p;
    }
  }
  for (int j = 0; j < 16; ++j)
    CS2[((size_t)b * 64 + dg * 16 + j) * 64 + m] = acc[j];
}

// Bm[d,k] = sum_m CS2[d,m] * S1[k,m]
__global__ __launch_bounds__(256) void k_cqBm(
    const float* __restrict__ C, const float* __restrict__ CS2,
    const float* __restrict__ S, const float* __restrict__ rmax,
    const float* __restrict__ rsum, float* __restrict__ Xcat) {
  int b = blockIdx.x, kt = blockIdx.y * 64;
  __shared__ float sW[4096];
  __shared__ float sP[64 * 65];
  for (int i = threadIdx.x; i < 4096; i += 256) sW[i] = CS2[(size_t)b * 4096 + i];
  for (int i = threadIdx.x; i < 4096; i += 256) {
    int kl = i >> 6, m = i & 63;
    int k = kt + kl;
    sP[kl * 65 + m] = __expf(S[((size_t)b * 256 + k) * 64 + m] - rmax[b * 256 + k]) / rsum[b * 256 + k];
  }
  __syncthreads();
  int kl = threadIdx.x & 63, dg = threadIdx.x >> 6;
  int k = kt + kl;
  for (int j = 0; j < 16; ++j) {
    int d = dg * 16 + j;
    float acc = 0.f;
    for (int m = 0; m < 64; ++m) acc += sW[d * 64 + m] * sP[kl * 65 + m];
    float cv = C[((size_t)b * 64 + d) * 256 + k];
    Xcat[((size_t)b * 256 + 192 + d) * 256 + k] = cv * acc;
  }
}

// ---- both pointers in one launch: grid (B, 2) ----------------------------
__global__ void k_pointer2(const float* __restrict__ M0, const float* __restrict__ M1,
                           const float* __restrict__ M2, const float* __restrict__ w0,
                           const float* __restrict__ w1, float* __restrict__ out) {
  int b = blockIdx.x, sel = blockIdx.y, n = threadIdx.x;
  const float* wb = (sel ? w1 : w0) + b * 128;
  const float* Mb = sel ? M2 : M1;
  float y = 0.f;
  for (int d = 0; d < 64; ++d) {
    y += wb[d] * M0[((size_t)b * 64 + d) * 256 + n];
    y += wb[64 + d] * Mb[((size_t)b * 64 + d) * 256 + n];
  }
  __shared__ float wred[4], wsum[4];
  int lane = n & 63, wid = n >> 6;
  float mx = y;
#pragma unroll
  for (int o = 32; o > 0; o >>= 1) mx = fmaxf(mx, __shfl_xor(mx, o));
  if (lane == 0) wred[wid] = mx;
  __syncthreads();
  mx = fmaxf(fmaxf(wred[0], wred[1]), fmaxf(wred[2], wred[3]));
  float e = __expf(y - mx);
  float s = e;
#pragma unroll
  for (int o = 32; o > 0; o >>= 1) s += __shfl_xor(s, o);
  if (lane == 0) wsum[wid] = s;
  __syncthreads();
  s = wsum[0] + wsum[1] + wsum[2] + wsum[3];
  out[sel * 6144 + b * 256 + n] = e / s;
}

// ===========================================================================
extern "C" void kernel_launch(void* const* d_in, const int* in_sizes, int n_in,
                              void* d_out, int out_size, void* d_ws, size_t ws_size,
                              hipStream_t stream) {
  const float* word_table = (const float*)d_in[0];
  const float* char_table = (const float*)d_in[1];
  const float* e2dw = (const float*)d_in[2];
  const float* e2db = (const float*)d_in[3];
  const float* e2pw = (const float*)d_in[4];
  const float* e2pb = (const float*)d_in[5];
  const float* e1dw = (const float*)d_in[6];
  const float* e1db = (const float*)d_in[7];
  const float* e1pw = (const float*)d_in[8];
  const float* e1pb = (const float*)d_in[9];
  const float* hlw = (const float*)d_in[10];
  const float* hlb = (const float*)d_in[11];
  const float* hgw = (const float*)d_in[12];
  const float* hgb = (const float*)d_in[13];
  const float *enc_dw[5], *enc_pw[5], *enc_wq[5], *enc_wk[5], *enc_wv[5], *enc_wo[5], *enc_w[5];
  for (int p = 0; p < 5; ++p) {
    enc_dw[p] = (const float*)d_in[14 + 7 * p + 0];
    enc_pw[p] = (const float*)d_in[14 + 7 * p + 1];
    enc_wq[p] = (const float*)d_in[14 + 7 * p + 2];
    enc_wk[p] = (const float*)d_in[14 + 7 * p + 3];
    enc_wv[p] = (const float*)d_in[14 + 7 * p + 4];
    enc_wo[p] = (const float*)d_in[14 + 7 * p + 5];
    enc_w[p]  = (const float*)d_in[14 + 7 * p + 6];
  }
  const float* cq_w  = (const float*)d_in[49];
  const float* rs_dw = (const float*)d_in[50];
  const float* rs_pw = (const float*)d_in[51];
  const float* p_w0  = (const float*)d_in[52];
  const float* p_w1  = (const float*)d_in[53];
  const int* Cwid = (const int*)d_in[54];
  const int* Ccid = (const int*)d_in[55];
  const int* Qwid = (const int*)d_in[56];
  const int* Qcid = (const int*)d_in[57];
  float* out = (float*)d_out;

  // ---- workspace (floats), ~12.3 MB --------------------------------------
  float* ws = (float*)d_ws;
  float* postab = ws;                  // 16384
  float* U    = ws + 16384;            // 393216  (att head out)
  float* Xcat = ws + 409600;           // 1572864 ; M2 aliases; emb scratch
  float* CX   = ws + 1982464;          // 393216  ; M0 aliases
  float* Sb   = ws + 2375680;          // 393216  ; M1 aliases
  float* QX   = ws + 2768896;          // 98304
  float* CS2  = ws + 2867200;          // 98304
  float* rmax = ws + 2965504;          // 6144
  float* rsum = ws + 2971648;          // 6144
  float* cmax = ws + 2977792;          // 1536
  float* csum = ws + 2979328;          // 1536
  float* P0   = ws + 2980864;          // 12288
  float* P1   = ws + 2993152;          // 12288
  float* pwT  = ws + 3005440;          // 12800
  float* e1pwT= ws + 3018240;          // 23296
  float* hlwT = ws + 3041536;          // 8192
  float* hgwT = ws + 3049728;          // 8192 -> ends 3057920
  float* M0 = CX; float* M1 = Sb; float* M2 = Xcat;
  float* E1 = Xcat; float* E2 = Xcat + 393216;
  (void)out_size; (void)in_sizes; (void)n_in; (void)ws_size;

  auto run_enc = [&](float* X, const float* src, int L, int cnum, int K, int p) {
    int NB = B * 64 / 4;
    if (src)
      hipLaunchKernelGGL((k_posadd_stats<true>), dim3(NB), dim3(256), 0, stream, X, src, postab, P0, L);
    else
      hipLaunchKernelGGL((k_posadd_stats<false>), dim3(NB), dim3(256), 0, stream, X, (const float*)nullptr, postab, P0, L);
    float* pin = P0; float* pout = P1;
    for (int i = 0; i < cnum; ++i) {
      if (K == 7)
        hipLaunchKernelGGL((k_fconv<7>), dim3(B, L / 64), dim3(256), 0, stream,
                           X, enc_dw[p] + i * 64 * 7, enc_pw[p] + (size_t)i * 4096, pin, pout, L);
      else
        hipLaunchKernelGGL((k_fconv<5>), dim3(B, L / 64), dim3(256), 0, stream,
                           X, enc_dw[p] + i * 64 * 5, enc_pw[p] + (size_t)i * 4096, pin, pout, L);
      float* t = pin; pin = pout; pout = t;
    }
    k_att<<<dim3(HH, B), 256, 0, stream>>>(X, pin, enc_wq[p], enc_wk[p], enc_wv[p], U, L);
    hipLaunchKernelGGL((k_matmul2<false, false, true>), dim3(B, L / 64), dim3(256), 0, stream,
                       U, enc_wo[p], (const float*)X, X, (const float*)nullptr, pout, L);
    hipLaunchKernelGGL((k_matmul2<true, true, false>), dim3(B, L / 64), dim3(256), 0, stream,
                       X, enc_w[p], (const float*)X, X, pout, (float*)nullptr, L);
  };

  k_postab<<<64, 256, 0, stream>>>(postab);
  k_pwT<<<50, 256, 0, stream>>>(e2pw, pwT);
  k_pwT2<<<91, 256, 0, stream>>>(e1pw, e1pwT);
  k_hwT<<<32, 256, 0, stream>>>(hlw, hlwT);
  k_hwT<<<32, 256, 0, stream>>>(hgw, hgwT);
  // ---- embeddings ----
  k_charembed<<<dim3(NN, B), 256, 0, stream>>>(Ccid, char_table, e2dw, e2db, pwT, e2pb, E1, NN);
  k_embconv<<<dim3(NN, B), 64, 0, stream>>>(E1, Cwid, word_table, e1dw, e1db, e1pwT, e1pb, E2, NN);
  k_highway<<<dim3(NN, B), 64, 0, stream>>>(E2, hlwT, hlb, hgwT, hgb, CX, NN);
  k_charembed<<<dim3(MQ, B), 256, 0, stream>>>(Qcid, char_table, e2dw, e2db, pwT, e2pb, E1, MQ);
  k_embconv<<<dim3(MQ, B), 64, 0, stream>>>(E1, Qwid, word_table, e1dw, e1db, e1pwT, e1pb, E2, MQ);
  k_highway<<<dim3(MQ, B), 64, 0, stream>>>(E2, hlwT, hlb, hgwT, hgb, QX, MQ);
  // ---- embedding encoders ----
  run_enc(CX, nullptr, 256, 4, 7, 0);
  run_enc(QX, nullptr, 64, 4, 7, 1);
  // ---- context-query attention ----
  k_cqS<<<dim3(B, 4), 256, 0, stream>>>(CX, QX, cq_w, Sb, rmax, rsum);
  k_cqcol<<<B, 64, 0, stream>>>(Sb, cmax, csum);
  k_cqA<<<dim3(B, 4), 256, 0, stream>>>(CX, QX, Sb, rmax, rsum, Xcat);
  k_cqCS2<<<B, 256, 0, stream>>>(CX, Sb, cmax, csum, CS2);
  k_cqBm<<<dim3(B, 4), 256, 0, stream>>>(CX, CS2, Sb, rmax, rsum, Xcat);
  // ---- resize -> M0 ----
  k_resize<<<dim3(B, 4), 256, 0, stream>>>(Xcat, rs_dw, rs_pw, M0);
  // ---- model encoders ----
  for (int r = 0; r < 7; ++r) run_enc(M0, nullptr, 256, 2, 5, 2);
  run_enc(M1, M0, 256, 2, 5, 3);
  for (int r = 1; r < 7; ++r) run_enc(M1, nullptr, 256, 2, 5, 3);
  run_enc(M2, M1, 256, 2, 5, 4);
  for (int r = 1; r < 7; ++r) run_enc(M2, nullptr, 256, 2, 5, 4);
  // ---- pointers ----
  k_pointer2<<<dim3(B, 2), 256, 0, stream>>>(M0, M1, M2, p_w0, p_w1, out);
}

// Round 15
// 3759.552 us; speedup vs baseline: 1.2328x; 1.0454x over previous
//
#include <hip/hip_runtime.h>
#include <math.h>

constexpr int B = 24, HH = 8;
constexpr int NN = 256, MQ = 64;
constexpr int EC = 364;

#define PI_2 1.5707963267948966f

// stats partials layout: parts[row][4][2], row = b*64+d
__device__ __forceinline__ void combine_stats(const float* __restrict__ parts,
                                              int row, int NT, float Lf,
                                              float& mu, float& inv) {
  float s = 0.f, q = 0.f;
  for (int t = 0; t < NT; ++t) {
    s += parts[((size_t)row * 4 + t) * 2];
    q += parts[((size_t)row * 4 + t) * 2 + 1];
  }
  mu = s / Lf;
  float var = (q - s * mu) / (Lf - 1.f);
  if (var < 0.f) var = 0.f;
  inv = 1.f / (sqrtf(var) + 1e-6f);
}

// ---------------- positional encoding table: tab[d*256+l] ----------------
__global__ void k_postab(float* __restrict__ tab) {
  int d = blockIdx.x, l = threadIdx.x;
  float fr = ((d & 1) == 0) ? powf(10000.f, -(float)d / 64.f)
                            : -powf(10000.f, -(float)(d - 1) / 64.f);
  float ph = (d & 1) ? PI_2 : 0.f;
  tab[d * 256 + l] = sinf(sinf((float)l * fr + ph));
}

// ---- weight transposes (one-time) ----------------------------------------
__global__ void k_pwT(const float* __restrict__ pw, float* __restrict__ pwT) {
  int i = blockIdx.x * 256 + threadIdx.x;
  if (i < 200 * 64) {
    int ce = i >> 6, o = i & 63;
    pwT[i] = pw[o * 200 + ce];
  }
}
__global__ void k_pwT2(const float* __restrict__ pw, float* __restrict__ pwT) {
  int i = blockIdx.x * 256 + threadIdx.x;
  if (i < EC * 64) {
    int c = i >> 6, o = i & 63;
    pwT[i] = pw[o * EC + c];
  }
}
__global__ void k_hwT(const float* __restrict__ w, float* __restrict__ wT) {
  int i = blockIdx.x * 256 + threadIdx.x;
  if (i < 8192) {
    int layer = i >> 12, rem = i & 4095;
    int d = rem >> 6, o = rem & 63;
    wT[i] = w[layer * 4096 + o * 64 + d];
  }
}
__global__ void k_dwT(const float* __restrict__ dw, float* __restrict__ dwT) {
  int i = blockIdx.x * 256 + threadIdx.x;
  if (i < 5000) {
    int t = i / 200, ce = i % 200;
    dwT[i] = dw[ce * 25 + t];
  }
}

// ---- X = (COPY? src : X) + tab ; emit per-tile row stats -----------------
template<bool COPY>
__global__ void k_posadd_stats(float* __restrict__ X, const float* __restrict__ src,
                               const float* __restrict__ tab, float* __restrict__ parts,
                               int L) {
  int row = blockIdx.x * 4 + (threadIdx.x >> 6);
  int lane = threadIdx.x & 63;
  int d = row & 63;
  float* xr = X + (size_t)row * L;
  const float* sr = COPY ? (src + (size_t)row * L) : xr;
  int NT = L >> 6;
  for (int t = 0; t < NT; ++t) {
    int l = t * 64 + lane;
    float v = sr[l] + tab[d * 256 + l];
    xr[l] = v;
    float s = v, q = v * v;
#pragma unroll
    for (int o = 32; o > 0; o >>= 1) { s += __shfl_xor(s, o); q += __shfl_xor(q, o); }
    if (lane == 0) {
      parts[((size_t)row * 4 + t) * 2] = s;
      parts[((size_t)row * 4 + t) * 2 + 1] = q;
    }
  }
}

// ---- fused: normalize -> dwconv(K) -> pw matmul -> relu -> +res -> X -----
template<int K>
__global__ __launch_bounds__(256) void k_fconv(
    float* __restrict__ X, const float* __restrict__ dw, const float* __restrict__ pw,
    const float* __restrict__ partsIn, float* __restrict__ partsOut, int L) {
  constexpr int H = K / 2, SW = 64 + 2 * H;
  __shared__ float smu[64], sinv[64];
  __shared__ float sN[64 * SW];
  __shared__ float sD[64 * 65];
  __shared__ __align__(16) float sWt[4096];
  int b = blockIdx.x, lt = blockIdx.y * 64;
  int tid = threadIdx.x;
  int NT = L >> 6;
  if (tid < 64) combine_stats(partsIn, b * 64 + tid, NT, (float)L, smu[tid], sinv[tid]);
  for (int i = tid; i < 1024; i += 256)
    ((float4*)sWt)[i] = ((const float4*)pw)[i];
  __syncthreads();
  float* Xb = X + (size_t)b * 64 * L;
  for (int i = tid; i < 64 * SW; i += 256) {
    int c = i / SW, jj = i % SW;
    int gl = lt + jj - H;
    sN[i] = (gl >= 0 && gl < L) ? (Xb[(size_t)c * L + gl] - smu[c]) * sinv[c] : 0.f;
  }
  __syncthreads();
  for (int i = tid; i < 4096; i += 256) {
    int c = i >> 6, l = i & 63;
    float acc = 0.f;
#pragma unroll
    for (int k = 0; k < K; ++k) acc += sN[c * SW + l + k] * dw[c * K + k];
    sD[c * 65 + l] = acc;
  }
  __syncthreads();
  int l = tid & 63, og = tid >> 6;
  float acc[16];
#pragma unroll
  for (int j = 0; j < 16; ++j) acc[j] = 0.f;
  for (int c = 0; c < 64; ++c) {
    float av = sD[c * 65 + l];
#pragma unroll
    for (int j = 0; j < 16; ++j) acc[j] += sWt[(og * 16 + j) * 64 + c] * av;
  }
  __syncthreads();
#pragma unroll
  for (int j = 0; j < 16; ++j) {
    int o = og * 16 + j;
    float v = Xb[(size_t)o * L + lt + l] + fmaxf(acc[j], 0.f);
    Xb[(size_t)o * L + lt + l] = v;
    sD[o * 65 + l] = v;
  }
  __syncthreads();
  if (tid < 64) {
    int o = tid;
    float s = 0.f, q = 0.f;
    for (int l2 = 0; l2 < 64; ++l2) { float v = sD[o * 65 + l2]; s += v; q += v * v; }
    partsOut[((size_t)(b * 64 + o) * 4 + blockIdx.y) * 2] = s;
    partsOut[((size_t)(b * 64 + o) * 4 + blockIdx.y) * 2 + 1] = q;
  }
}

// ---- generic 64x64 matmul: out = res + act(W . (norm?)A) [+tab] ; stats --
template<bool NORM, bool RELU, bool STATS, bool ADDTAB>
__global__ __launch_bounds__(256) void k_matmul2(
    const float* __restrict__ A, const float* __restrict__ W,
    const float* __restrict__ res, float* __restrict__ out,
    const float* __restrict__ partsIn, float* __restrict__ partsOut,
    const float* __restrict__ tab, int L) {
  __shared__ float sA[64 * 65];
  __shared__ __align__(16) float sW[4096];
  __shared__ float smu[64], sinv[64];
  int b = blockIdx.x, lt = blockIdx.y * 64;
  int tid = threadIdx.x;
  int NT = L >> 6;
  if (NORM && tid < 64) combine_stats(partsIn, b * 64 + tid, NT, (float)L, smu[tid], sinv[tid]);
  const float* Wb = W + (size_t)b * 4096;
  for (int i = tid; i < 1024; i += 256)
    ((float4*)sW)[i] = ((const float4*)Wb)[i];
  if (NORM) __syncthreads();
  const float* Ab = A + (size_t)b * 64 * L;
  for (int i = tid; i < 1024; i += 256) {
    int c = i >> 4, lq = (i & 15) * 4;
    float4 v = *(const float4*)(Ab + (size_t)c * L + lt + lq);
    if (NORM) {
      float mu = smu[c], iv = sinv[c];
      v.x = (v.x - mu) * iv; v.y = (v.y - mu) * iv;
      v.z = (v.z - mu) * iv; v.w = (v.w - mu) * iv;
    }
    sA[c * 65 + lq] = v.x; sA[c * 65 + lq + 1] = v.y;
    sA[c * 65 + lq + 2] = v.z; sA[c * 65 + lq + 3] = v.w;
  }
  __syncthreads();
  int l = tid & 63, og = tid >> 6;
  float acc[16];
#pragma unroll
  for (int j = 0; j < 16; ++j) acc[j] = 0.f;
  for (int c = 0; c < 64; ++c) {
    float av = sA[c * 65 + l];
#pragma unroll
    for (int j = 0; j < 16; ++j) acc[j] += sW[(og * 16 + j) * 64 + c] * av;
  }
  if (STATS) __syncthreads();
#pragma unroll
  for (int j = 0; j < 16; ++j) {
    int o = og * 16 + j;
    float v = acc[j];
    if (RELU) v = fmaxf(v, 0.f);
    size_t idx = ((size_t)b * 64 + o) * L + lt + l;
    v += res[idx];
    if (ADDTAB) v += tab[o * 256 + lt + l];
    out[idx] = v;
    if (STATS) sA[o * 65 + l] = v;
  }
  if (STATS) {
    __syncthreads();
    if (tid < 64) {
      int o = tid;
      float s = 0.f, q = 0.f;
      for (int l2 = 0; l2 < 64; ++l2) { float v = sA[o * 65 + l2]; s += v; q += v * v; }
      partsOut[((size_t)(b * 64 + o) * 4 + blockIdx.y) * 2] = s;
      partsOut[((size_t)(b * 64 + o) * 4 + blockIdx.y) * 2 + 1] = q;
    }
  }
}

// ---- fused resize: M0[b,o,l] = sum_c pw[o,c] * dw5(Xcat)[b,c,l] ----------
__global__ __launch_bounds__(256) void k_resize(
    const float* __restrict__ Xcat, const float* __restrict__ dw,
    const float* __restrict__ pw, float* __restrict__ out) {
  __shared__ float sA[64 * 64];
  int b = blockIdx.x, lt = blockIdx.y * 64;
  int l = threadIdx.x & 63, og = threadIdx.x >> 6;
  float acc[16];
#pragma unroll
  for (int j = 0; j < 16; ++j) acc[j] = 0.f;
  for (int c0 = 0; c0 < 256; c0 += 64) {
    __syncthreads();
    for (int i = threadIdx.x; i < 4096; i += 256) {
      int c = (i >> 6) + c0, ll = (i & 63) + lt;
      const float* xr = Xcat + ((size_t)b * 256 + c) * 256;
      float a = 0.f;
#pragma unroll
      for (int k = 0; k < 5; ++k) {
        int p = ll + k - 2;
        if (p >= 0 && p < 256) a += xr[p] * dw[c * 5 + k];
      }
      sA[i] = a;
    }
    __syncthreads();
    for (int c = 0; c < 64; ++c) {
      float av = sA[c * 64 + l];
#pragma unroll
      for (int j = 0; j < 16; ++j)
        acc[j] += pw[(size_t)(og * 16 + j) * 256 + c0 + c] * av;
    }
  }
#pragma unroll
  for (int j = 0; j < 16; ++j)
    out[((size_t)b * 64 + og * 16 + j) * 256 + lt + l] = acc[j];
}

// ---- self-attention with inline norm, online softmax ---------------------
__global__ __launch_bounds__(256) void k_att(
    const float* __restrict__ X, const float* __restrict__ partsIn,
    const float* __restrict__ wq, const float* __restrict__ wk,
    const float* __restrict__ wv, float* __restrict__ hc, int L) {
  int h = blockIdx.x, b = blockIdx.y;
  __shared__ float smu[64], sinv[64];
  __shared__ float sX[64 * 65];
  __shared__ float sQ[8 * 256], sK8[8 * 256], sV[8 * 256];
  __shared__ float swq[512], swk[512], swv[512];
  int tid = threadIdx.x;
  int NT = L >> 6;
  if (tid < 64) combine_stats(partsIn, b * 64 + tid, NT, (float)L, smu[tid], sinv[tid]);
  size_t woff = (size_t)(h * B + b) * 512;
  for (int i = tid; i < 512; i += 256) {
    swq[i] = wq[woff + i]; swk[i] = wk[woff + i]; swv[i] = wv[woff + i];
  }
  __syncthreads();
  const float* Xb = X + (size_t)b * 64 * L;
  for (int lt = 0; lt < L; lt += 64) {
    for (int i = tid; i < 4096; i += 256) {
      int d = i >> 6, l = i & 63;
      sX[d * 65 + l] = (Xb[(size_t)d * L + lt + l] - smu[d]) * sinv[d];
    }
    __syncthreads();
    for (int i = tid; i < 512; i += 256) {
      int k = i >> 6, l = i & 63;
      float aq = 0.f, ak = 0.f, av = 0.f;
      for (int d = 0; d < 64; ++d) {
        float x = sX[d * 65 + l];
        aq += swq[k * 64 + d] * x;
        ak += swk[k * 64 + d] * x;
        av += swv[k * 64 + d] * x;
      }
      sQ[k * L + lt + l] = aq; sK8[k * L + lt + l] = ak; sV[k * L + lt + l] = av;
    }
    __syncthreads();
  }
  const float scale = 0.35355339059327373f;  // 1/sqrt(8)
  for (int m = tid; m < L; m += 256) {
    float kc[8];
#pragma unroll
    for (int k = 0; k < 8; ++k) kc[k] = sK8[k * L + m];
    float mx = -1e30f, sum = 0.f, acc[8];
#pragma unroll
    for (int v = 0; v < 8; ++v) acc[v] = 0.f;
    for (int l = 0; l < L; ++l) {
      float s = 0.f;
#pragma unroll
      for (int k = 0; k < 8; ++k) s += sQ[k * L + l] * kc[k];
      s *= scale;
      if (s <= mx) {
        float p = __expf(s - mx);
        sum += p;
#pragma unroll
        for (int v = 0; v < 8; ++v) acc[v] += p * sV[v * L + l];
      } else {
        float corr = __expf(mx - s);
        sum = sum * corr + 1.f;
#pragma unroll
        for (int v = 0; v < 8; ++v) acc[v] = acc[v] * corr + sV[v * L + l];
        mx = s;
      }
    }
    float is = 1.f / sum;
    for (int v = 0; v < 8; ++v)
      hc[((size_t)b * 64 + h * 8 + v) * L + m] = acc[v] * is;
  }
}

// ---- fused char embed: register-staged taps + transposed dw/pw -----------
__global__ __launch_bounds__(256) void k_charembed(
    const int* __restrict__ cid, const float* __restrict__ ctab,
    const float* __restrict__ dwT, const float* __restrict__ db,
    const float* __restrict__ pwT, const float* __restrict__ pb,
    float* __restrict__ out, int Ln) {
  int n = blockIdx.x, b = blockIdx.y;
  __shared__ float dwo[16 * 200];   // [cn][ce]
  __shared__ int sid[5][16];
  __shared__ float red[256];
  int tid = threadIdx.x;
  if (tid < 80) {
    int kn = tid / 16, cn = tid % 16;
    int nn = n + kn - 2;
    sid[kn][cn] = (nn >= 0 && nn < Ln) ? cid[((size_t)b * Ln + nn) * 16 + cn] : -1;
  }
  __syncthreads();
  for (int i = tid; i < 16 * 200; i += 256) {
    int cn = i / 200, ce = i % 200;
    float r[25];
#pragma unroll
    for (int kn = 0; kn < 5; ++kn) {
#pragma unroll
      for (int kc = 0; kc < 5; ++kc) {
        int cc = cn + kc - 2;
        int id = (cc >= 0 && cc < 16) ? sid[kn][cc] : -1;
        r[kn * 5 + kc] = (id >= 0) ? ctab[(size_t)id * 200 + ce] : 0.f;
      }
    }
    float acc = db[ce];
#pragma unroll
    for (int t = 0; t < 25; ++t) acc += r[t] * dwT[t * 200 + ce];
    dwo[cn * 200 + ce] = acc;
  }
  __syncthreads();
  int o = tid & 63, q = tid >> 6;
  float mx = -1e30f;
  for (int cn = q; cn < 16; cn += 4) {
    float acc = pb[o];
    const float* dr = dwo + cn * 200;
    for (int c0 = 0; c0 < 200; c0 += 8) {
      float w8[8];
#pragma unroll
      for (int j = 0; j < 8; ++j) w8[j] = pwT[(c0 + j) * 64 + o];
#pragma unroll
      for (int j = 0; j < 8; ++j) acc += w8[j] * dr[c0 + j];
    }
    mx = fmaxf(mx, acc);
  }
  red[tid] = mx;
  __syncthreads();
  if (q == 0) {
    mx = fmaxf(fmaxf(red[o], red[64 + o]), fmaxf(red[128 + o], red[192 + o]));
    out[((size_t)b * 64 + o) * Ln + n] = fmaxf(mx, 0.f);
  }
}

// ---- fused emb conv: transposed pw + chunked register staging ------------
__global__ void k_embconv(const float* __restrict__ chx, const int* __restrict__ wid,
                          const float* __restrict__ wtab, const float* __restrict__ dw,
                          const float* __restrict__ db, const float* __restrict__ pwT,
                          const float* __restrict__ pb, float* __restrict__ out, int Ln) {
  int n = blockIdx.x, b = blockIdx.y;
  __shared__ float dwc[EC];
  __shared__ int sw[5];
  int tid = threadIdx.x;
  if (tid < 5) {
    int nn = n + tid - 2;
    sw[tid] = (nn >= 0 && nn < Ln) ? wid[(size_t)b * Ln + nn] : -1;
  }
  __syncthreads();
  for (int ch = tid; ch < EC; ch += 64) {
    float r[5];
#pragma unroll
    for (int k = 0; k < 5; ++k) {
      int nn = n + k - 2;
      float v = 0.f;
      if (nn >= 0 && nn < Ln) {
        if (ch < 64) v = chx[((size_t)b * 64 + ch) * Ln + nn];
        else v = wtab[(size_t)sw[k] * 300 + (ch - 64)];
      }
      r[k] = v;
    }
    float acc = db[ch];
#pragma unroll
    for (int k = 0; k < 5; ++k) acc += r[k] * dw[ch * 5 + k];
    dwc[ch] = acc;
  }
  __syncthreads();
  int o = tid;
  float acc = pb[o];
  for (int c0 = 0; c0 < EC; c0 += 4) {
    float w4[4];
#pragma unroll
    for (int j = 0; j < 4; ++j) w4[j] = pwT[(c0 + j) * 64 + o];
#pragma unroll
    for (int j = 0; j < 4; ++j) acc += w4[j] * dwc[c0 + j];
  }
  out[((size_t)b * 64 + o) * Ln + n] = acc;
}

// ---------------- highway: transposed weights + chunked staging -----------
__global__ void k_highway(const float* __restrict__ inx, const float* __restrict__ lwT,
                          const float* __restrict__ lb, const float* __restrict__ gwT,
                          const float* __restrict__ gb, float* __restrict__ out, int Ln) {
  int n = blockIdx.x, b = blockIdx.y;
  __shared__ float x[64], xn[64];
  int o = threadIdx.x;
  x[o] = inx[((size_t)b * 64 + o) * Ln + n];
  __syncthreads();
  for (int layer = 0; layer < 2; ++layer) {
    const float* lwr = lwT + layer * 4096;
    const float* gwr = gwT + layer * 4096;
    float gl = gb[layer * 64 + o], nl = lb[layer * 64 + o];
    for (int d0 = 0; d0 < 64; d0 += 8) {
      float g8[8], l8[8];
#pragma unroll
      for (int j = 0; j < 8; ++j) { g8[j] = gwr[(d0 + j) * 64 + o]; l8[j] = lwr[(d0 + j) * 64 + o]; }
#pragma unroll
      for (int j = 0; j < 8; ++j) { gl += g8[j] * x[d0 + j]; nl += l8[j] * x[d0 + j]; }
    }
    float g = 1.f / (1.f + __expf(-gl));
    float r = fmaxf(nl, 0.f);
    xn[o] = g * r + (1.f - g) * x[o];
    __syncthreads();
    x[o] = xn[o];
    __syncthreads();
  }
  out[((size_t)b * 64 + o) * Ln + n] = x[o];
}

// ---------------- context-query attention ---------------------------------
__global__ __launch_bounds__(256) void k_cqS(const float* __restrict__ C,
                                             const float* __restrict__ Q,
                                             const float* __restrict__ w,
                                             float* __restrict__ S,
                                             float* __restrict__ rmax,
                                             float* __restrict__ rsum) {
  int b = blockIdx.x, nt = blockIdx.y * 64;
  __shared__ float sQ[4096], sC[4096], ct[64], qt[64], swb[192];
  const float* Cb = C + (size_t)b * 64 * 256;
  const float* Qb = Q + (size_t)b * 4096;
  const float* wb = w + (size_t)b * 192;
  if (threadIdx.x < 192) swb[threadIdx.x] = wb[threadIdx.x];
  for (int i = threadIdx.x; i < 4096; i += 256) {
    int d = i >> 6, m = i & 63;
    sQ[i] = Qb[d * 64 + m];
    sC[i] = Cb[d * 256 + nt + m];
  }
  __syncthreads();
  if (threadIdx.x < 64) {
    int j = threadIdx.x;
    float a = 0.f, c2 = 0.f;
    for (int d = 0; d < 64; ++d) {
      a += swb[64 + d] * sC[d * 64 + j];
      c2 += swb[d] * sQ[d * 64 + j];
    }
    ct[j] = a; qt[j] = c2;
  }
  __syncthreads();
  int m = threadIdx.x & 63, wv = threadIdx.x >> 6;
  for (int it = 0; it < 16; ++it) {
    int nl = wv + it * 4;
    float acc = ct[nl] + qt[m];
    for (int d = 0; d < 64; ++d)
      acc += sC[d * 64 + nl] * swb[128 + d] * sQ[d * 64 + m];
    S[((size_t)b * 256 + nt + nl) * 64 + m] = acc;
    float mx = acc;
#pragma unroll
    for (int o = 32; o > 0; o >>= 1) mx = fmaxf(mx, __shfl_xor(mx, o));
    float p = __expf(acc - mx);
#pragma unroll
    for (int o = 32; o > 0; o >>= 1) p += __shfl_xor(p, o);
    if (m == 0) { rmax[b * 256 + nt + nl] = mx; rsum[b * 256 + nt + nl] = p; }
  }
}

__global__ void k_cqcol(const float* __restrict__ S, float* __restrict__ cmax,
                        float* __restrict__ csum) {
  int b = blockIdx.x, m = threadIdx.x;
  const float* Sb = S + (size_t)b * 256 * 64;
  float mx = -1e30f;
  for (int n = 0; n < 256; ++n) mx = fmaxf(mx, Sb[n * 64 + m]);
  float s = 0.f;
  for (int n = 0; n < 256; ++n) s += __expf(Sb[n * 64 + m] - mx);
  cmax[b * 64 + m] = mx; csum[b * 64 + m] = s;
}

__global__ __launch_bounds__(256) void k_cqA(
    const float* __restrict__ C, const float* __restrict__ Q,
    const float* __restrict__ S, const float* __restrict__ rmax,
    const float* __restrict__ rsum, float* __restrict__ Xcat) {
  int b = blockIdx.x, nt = blockIdx.y * 64;
  __shared__ float sQ[4096];
  __shared__ float sP[64 * 65];
  const float* Qb = Q + (size_t)b * 4096;
  for (int i = threadIdx.x; i < 4096; i += 256) sQ[i] = Qb[i];
  for (int i = threadIdx.x; i < 4096; i += 256) {
    int nl = i >> 6, m = i & 63;
    int n = nt + nl;
    sP[nl * 65 + m] = __expf(S[((size_t)b * 256 + n) * 64 + m] - rmax[b * 256 + n]) / rsum[b * 256 + n];
  }
  __syncthreads();
  int nl = threadIdx.x & 63, dg = threadIdx.x >> 6;
  int n = nt + nl;
  for (int j = 0; j < 16; ++j) {
    int d = dg * 16 + j;
    float acc = 0.f;
    for (int m = 0; m < 64; ++m) acc += sQ[d * 64 + m] * sP[nl * 65 + m];
    float cv = C[((size_t)b * 64 + d) * 256 + n];
    Xcat[((size_t)b * 256 + d) * 256 + n] = cv;
    Xcat[((size_t)b * 256 + 64 + d) * 256 + n] = acc;
    Xcat[((size_t)b * 256 + 128 + d) * 256 + n] = cv * acc;
  }
}

// CS2[d,m] = sum_n C[d,n] * S2[n,m]
__global__ __launch_bounds__(256) void k_cqCS2(
    const float* __restrict__ C, const float* __restrict__ S,
    const float* __restrict__ cmax, const float* __restrict__ csum,
    float* __restrict__ CS2) {
  int b = blockIdx.x;
  __shared__ float sP[4096], sC[4096];
  int m = threadIdx.x & 63, dg = threadIdx.x >> 6;
  float acc[16];
#pragma unroll
  for (int j = 0; j < 16; ++j) acc[j] = 0.f;
  for (int nt = 0; nt < 4; ++nt) {
    __syncthreads();
    for (int i = threadIdx.x; i < 4096; i += 256) {
      int nl = i >> 6, mm = i & 63;
      int n = nt * 64 + nl;
      sP[i] = __expf(S[((size_t)b * 256 + n) * 64 + mm] - cmax[b * 64 + mm]) / csum[b * 64 + mm];
      int d = i >> 6, nn = i & 63;
      sC[i] = C[((size_t)b * 64 + d) * 256 + nt * 64 + nn];
    }
    __syncthreads();
    for (int nl = 0; nl < 64; ++nl) {
      float p = sP[nl * 64 + m];
#pragma unroll
      for (int j = 0; j < 16; ++j) acc[j] += sC[(dg * 16 + j) * 64 + nl] * p;
    }
  }
  for (int j = 0; j < 16; ++j)
    CS2[((size_t)b * 64 + dg * 16 + j) * 64 + m] = acc[j];
}

// Bm[d,k] = sum_m CS2[d,m] * S1[k,m]
__global__ __launch_bounds__(256) void k_cqBm(
    const float* __restrict__ C, const float* __restrict__ CS2,
    const float* __restrict__ S, const float* __restrict__ rmax,
    const float* __restrict__ rsum, float* __restrict__ Xcat) {
  int b = blockIdx.x, kt = blockIdx.y * 64;
  __shared__ float sW[4096];
  __shared__ float sP[64 * 65];
  for (int i = threadIdx.x; i < 4096; i += 256) sW[i] = CS2[(size_t)b * 4096 + i];
  for (int i = threadIdx.x; i < 4096; i += 256) {
    int kl = i >> 6, m = i & 63;
    int k = kt + kl;
    sP[kl * 65 + m] = __expf(S[((size_t)b * 256 + k) * 64 + m] - rmax[b * 256 + k]) / rsum[b * 256 + k];
  }
  __syncthreads();
  int kl = threadIdx.x & 63, dg = threadIdx.x >> 6;
  int k = kt + kl;
  for (int j = 0; j < 16; ++j) {
    int d = dg * 16 + j;
    float acc = 0.f;
    for (int m = 0; m < 64; ++m) acc += sW[d * 64 + m] * sP[kl * 65 + m];
    float cv = C[((size_t)b * 64 + d) * 256 + k];
    Xcat[((size_t)b * 256 + 192 + d) * 256 + k] = cv * acc;
  }
}

// ---- both pointers in one launch: grid (B, 2) ----------------------------
__global__ void k_pointer2(const float* __restrict__ M0, const float* __restrict__ M1,
                           const float* __restrict__ M2, const float* __restrict__ w0,
                           const float* __restrict__ w1, float* __restrict__ out) {
  int b = blockIdx.x, sel = blockIdx.y, n = threadIdx.x;
  const float* wb = (sel ? w1 : w0) + b * 128;
  const float* Mb = sel ? M2 : M1;
  float y = 0.f;
  for (int d = 0; d < 64; ++d) {
    y += wb[d] * M0[((size_t)b * 64 + d) * 256 + n];
    y += wb[64 + d] * Mb[((size_t)b * 64 + d) * 256 + n];
  }
  __shared__ float wred[4], wsum[4];
  int lane = n & 63, wid = n >> 6;
  float mx = y;
#pragma unroll
  for (int o = 32; o > 0; o >>= 1) mx = fmaxf(mx, __shfl_xor(mx, o));
  if (lane == 0) wred[wid] = mx;
  __syncthreads();
  mx = fmaxf(fmaxf(wred[0], wred[1]), fmaxf(wred[2], wred[3]));
  float e = __expf(y - mx);
  float s = e;
#pragma unroll
  for (int o = 32; o > 0; o >>= 1) s += __shfl_xor(s, o);
  if (lane == 0) wsum[wid] = s;
  __syncthreads();
  s = wsum[0] + wsum[1] + wsum[2] + wsum[3];
  out[sel * 6144 + b * 256 + n] = e / s;
}

// ===========================================================================
extern "C" void kernel_launch(void* const* d_in, const int* in_sizes, int n_in,
                              void* d_out, int out_size, void* d_ws, size_t ws_size,
                              hipStream_t stream) {
  const float* word_table = (const float*)d_in[0];
  const float* char_table = (const float*)d_in[1];
  const float* e2dw = (const float*)d_in[2];
  const float* e2db = (const float*)d_in[3];
  const float* e2pw = (const float*)d_in[4];
  const float* e2pb = (const float*)d_in[5];
  const float* e1dw = (const float*)d_in[6];
  const float* e1db = (const float*)d_in[7];
  const float* e1pw = (const float*)d_in[8];
  const float* e1pb = (const float*)d_in[9];
  const float* hlw = (const float*)d_in[10];
  const float* hlb = (const float*)d_in[11];
  const float* hgw = (const float*)d_in[12];
  const float* hgb = (const float*)d_in[13];
  const float *enc_dw[5], *enc_pw[5], *enc_wq[5], *enc_wk[5], *enc_wv[5], *enc_wo[5], *enc_w[5];
  for (int p = 0; p < 5; ++p) {
    enc_dw[p] = (const float*)d_in[14 + 7 * p + 0];
    enc_pw[p] = (const float*)d_in[14 + 7 * p + 1];
    enc_wq[p] = (const float*)d_in[14 + 7 * p + 2];
    enc_wk[p] = (const float*)d_in[14 + 7 * p + 3];
    enc_wv[p] = (const float*)d_in[14 + 7 * p + 4];
    enc_wo[p] = (const float*)d_in[14 + 7 * p + 5];
    enc_w[p]  = (const float*)d_in[14 + 7 * p + 6];
  }
  const float* cq_w  = (const float*)d_in[49];
  const float* rs_dw = (const float*)d_in[50];
  const float* rs_pw = (const float*)d_in[51];
  const float* p_w0  = (const float*)d_in[52];
  const float* p_w1  = (const float*)d_in[53];
  const int* Cwid = (const int*)d_in[54];
  const int* Ccid = (const int*)d_in[55];
  const int* Qwid = (const int*)d_in[56];
  const int* Qcid = (const int*)d_in[57];
  float* out = (float*)d_out;

  // ---- workspace (floats), ~12.3 MB --------------------------------------
  float* ws = (float*)d_ws;
  float* postab = ws;                  // 16384
  float* U    = ws + 16384;            // 393216  (att head out)
  float* Xcat = ws + 409600;           // 1572864 ; M2 aliases; emb scratch
  float* CX   = ws + 1982464;          // 393216  ; M0 aliases
  float* Sb   = ws + 2375680;          // 393216  ; M1 aliases
  float* QX   = ws + 2768896;          // 98304
  float* CS2  = ws + 2867200;          // 98304
  float* rmax = ws + 2965504;          // 6144
  float* rsum = ws + 2971648;          // 6144
  float* cmax = ws + 2977792;          // 1536
  float* csum = ws + 2979328;          // 1536
  float* P0   = ws + 2980864;          // 12288
  float* P1   = ws + 2993152;          // 12288
  float* pwT  = ws + 3005440;          // 12800
  float* e1pwT= ws + 3018240;          // 23296
  float* hlwT = ws + 3041536;          // 8192
  float* hgwT = ws + 3049728;          // 8192
  float* dwT  = ws + 3057920;          // 5000 -> ends 3062920
  float* M0 = CX; float* M1 = Sb; float* M2 = Xcat;
  float* E1 = Xcat; float* E2 = Xcat + 393216;
  (void)out_size; (void)in_sizes; (void)n_in; (void)ws_size;

  // encoder stack: posadd once; per rep: cnum x fconv, att, wo(stats), FF.
  // mid-rep FF folds next rep's posadd (ADDTAB) + emits stats -> P0.
  auto run_enc = [&](float* X, const float* src, int L, int cnum, int K, int p, int reps) {
    int NB = B * 64 / 4;
    if (src)
      hipLaunchKernelGGL((k_posadd_stats<true>), dim3(NB), dim3(256), 0, stream, X, src, postab, P0, L);
    else
      hipLaunchKernelGGL((k_posadd_stats<false>), dim3(NB), dim3(256), 0, stream, X, (const float*)nullptr, postab, P0, L);
    for (int rep = 0; rep < reps; ++rep) {
      float* pin = P0; float* pout = P1;
      for (int i = 0; i < cnum; ++i) {
        if (K == 7)
          hipLaunchKernelGGL((k_fconv<7>), dim3(B, L / 64), dim3(256), 0, stream,
                             X, enc_dw[p] + i * 64 * 7, enc_pw[p] + (size_t)i * 4096, pin, pout, L);
        else
          hipLaunchKernelGGL((k_fconv<5>), dim3(B, L / 64), dim3(256), 0, stream,
                             X, enc_dw[p] + i * 64 * 5, enc_pw[p] + (size_t)i * 4096, pin, pout, L);
        float* t = pin; pin = pout; pout = t;
      }
      k_att<<<dim3(HH, B), 256, 0, stream>>>(X, pin, enc_wq[p], enc_wk[p], enc_wv[p], U, L);
      hipLaunchKernelGGL((k_matmul2<false, false, true, false>), dim3(B, L / 64), dim3(256), 0, stream,
                         U, enc_wo[p], (const float*)X, X, (const float*)nullptr, pout,
                         (const float*)nullptr, L);
      if (rep + 1 < reps)
        hipLaunchKernelGGL((k_matmul2<true, true, true, true>), dim3(B, L / 64), dim3(256), 0, stream,
                           X, enc_w[p], (const float*)X, X, pout, P0, (const float*)postab, L);
      else
        hipLaunchKernelGGL((k_matmul2<true, true, false, false>), dim3(B, L / 64), dim3(256), 0, stream,
                           X, enc_w[p], (const float*)X, X, pout, (float*)nullptr,
                           (const float*)nullptr, L);
    }
  };

  k_postab<<<64, 256, 0, stream>>>(postab);
  k_pwT<<<50, 256, 0, stream>>>(e2pw, pwT);
  k_pwT2<<<91, 256, 0, stream>>>(e1pw, e1pwT);
  k_hwT<<<32, 256, 0, stream>>>(hlw, hlwT);
  k_hwT<<<32, 256, 0, stream>>>(hgw, hgwT);
  k_dwT<<<20, 256, 0, stream>>>(e2dw, dwT);
  // ---- embeddings ----
  k_charembed<<<dim3(NN, B), 256, 0, stream>>>(Ccid, char_table, dwT, e2db, pwT, e2pb, E1, NN);
  k_embconv<<<dim3(NN, B), 64, 0, stream>>>(E1, Cwid, word_table, e1dw, e1db, e1pwT, e1pb, E2, NN);
  k_highway<<<dim3(NN, B), 64, 0, stream>>>(E2, hlwT, hlb, hgwT, hgb, CX, NN);
  k_charembed<<<dim3(MQ, B), 256, 0, stream>>>(Qcid, char_table, dwT, e2db, pwT, e2pb, E1, MQ);
  k_embconv<<<dim3(MQ, B), 64, 0, stream>>>(E1, Qwid, word_table, e1dw, e1db, e1pwT, e1pb, E2, MQ);
  k_highway<<<dim3(MQ, B), 64, 0, stream>>>(E2, hlwT, hlb, hgwT, hgb, QX, MQ);
  // ---- embedding encoders ----
  run_enc(CX, nullptr, 256, 4, 7, 0, 1);
  run_enc(QX, nullptr, 64, 4, 7, 1, 1);
  // ---- context-query attention ----
  k_cqS<<<dim3(B, 4), 256, 0, stream>>>(CX, QX, cq_w, Sb, rmax, rsum);
  k_cqcol<<<B, 64, 0, stream>>>(Sb, cmax, csum);
  k_cqA<<<dim3(B, 4), 256, 0, stream>>>(CX, QX, Sb, rmax, rsum, Xcat);
  k_cqCS2<<<B, 256, 0, stream>>>(CX, Sb, cmax, csum, CS2);
  k_cqBm<<<dim3(B, 4), 256, 0, stream>>>(CX, CS2, Sb, rmax, rsum, Xcat);
  // ---- resize -> M0 ----
  k_resize<<<dim3(B, 4), 256, 0, stream>>>(Xcat, rs_dw, rs_pw, M0);
  // ---- model encoders ----
  run_enc(M0, nullptr, 256, 2, 5, 2, 7);
  run_enc(M1, M0, 256, 2, 5, 3, 7);
  run_enc(M2, M1, 256, 2, 5, 4, 7);
  // ---- pointers ----
  k_pointer2<<<dim3(B, 2), 256, 0, stream>>>(M0, M1, M2, p_w0, p_w1, out);
}